// Round 3
// baseline (1143.939 us; speedup 1.0000x reference)
//
#include <hip/hip_runtime.h>
#include <math.h>

#define N_IN_F 28
#define N_HID 16
#define NPB 256            // nodes per bucket (bucket = dst >> 8)
#define NB_MAX 1024        // scan / hist capacity (782 actual)
#define EPB 8192           // edges per binning block
#define SRC_BITS 18
#define SRC_MASK ((1 << SRC_BITS) - 1)

// ---------------- build: degree + bucket bases + binned edges ----------------

__global__ void k_zero_deg(int* __restrict__ deg, int n) {
    int i = blockIdx.x * blockDim.x + threadIdx.x;
    if (i < n) deg[i] = 0;
}

__global__ void k_deg(const int* __restrict__ dst, int* __restrict__ deg, int ne) {
    int e = blockIdx.x * blockDim.x + threadIdx.x;
    if (e < ne) atomicAdd(&deg[dst[e]], 1);
}

// one 256-thread block per bucket: bcnt[b] = sum(deg[b*256 .. b*256+255])
__global__ void k_bucket_cnt(const int* __restrict__ deg, int* __restrict__ bcnt, int n) {
    __shared__ int sm[NPB];
    int b = blockIdx.x;
    int i = b * NPB + threadIdx.x;
    sm[threadIdx.x] = (i < n) ? deg[i] : 0;
    __syncthreads();
    for (int off = NPB / 2; off > 0; off >>= 1) {
        if (threadIdx.x < off) sm[threadIdx.x] += sm[threadIdx.x + off];
        __syncthreads();
    }
    if (threadIdx.x == 0) bcnt[b] = sm[0];
}

// single block of 1024: exclusive scan of bcnt[nb] -> base, cursor
__global__ void k_scan(const int* __restrict__ bcnt, int* __restrict__ base,
                       int* __restrict__ cursor, int nb, int ne) {
    __shared__ int sm[1024];
    int v = (threadIdx.x < nb) ? bcnt[threadIdx.x] : 0;
    sm[threadIdx.x] = v;
    __syncthreads();
    for (int off = 1; off < 1024; off <<= 1) {
        int t = (threadIdx.x >= off) ? sm[threadIdx.x - off] : 0;
        __syncthreads();
        sm[threadIdx.x] += t;
        __syncthreads();
    }
    if (threadIdx.x < nb) {
        int ex = sm[threadIdx.x] - v;
        base[threadIdx.x] = ex;
        cursor[threadIdx.x] = ex;
    }
    if (threadIdx.x == 0) base[nb] = ne;
}

// bin edges by bucket: LDS count -> one global atomic per (block,bucket) -> scatter
__global__ void __launch_bounds__(256)
k_bin(const int* __restrict__ src, const int* __restrict__ dst,
      int* __restrict__ cursor, int* __restrict__ binned, int ne, int nb) {
    __shared__ int hist[NB_MAX];
    __shared__ int lc[NB_MAX];
    int tid = threadIdx.x;
    for (int t = tid; t < nb; t += 256) hist[t] = 0;
    __syncthreads();
    int e0 = blockIdx.x * EPB;
    int e1 = min(e0 + EPB, ne);
    for (int e = e0 + tid; e < e1; e += 256) atomicAdd(&hist[dst[e] >> 8], 1);
    __syncthreads();
    for (int t = tid; t < nb; t += 256) {
        int c = hist[t];
        lc[t] = c ? atomicAdd(&cursor[t], c) : 0;
    }
    __syncthreads();
    for (int e = e0 + tid; e < e1; e += 256) {
        int d = dst[e];
        int b = d >> 8;
        int pos = atomicAdd(&lc[b], 1);
        binned[pos] = src[e] | ((d & (NPB - 1)) << SRC_BITS);
    }
}

// ---------------- compute ----------------

// per-node: dis = rsqrt(deg+1); hs1 = (x @ W1) * dis
__global__ void k_h1(const float* __restrict__ x, const float* __restrict__ W1,
                     const int* __restrict__ deg, float* __restrict__ dis,
                     float* __restrict__ hs1, int n) {
    __shared__ float w[N_IN_F * N_HID];
    for (int t = threadIdx.x; t < N_IN_F * N_HID; t += blockDim.x) w[t] = W1[t];
    __syncthreads();
    int i = blockIdx.x * blockDim.x + threadIdx.x;
    if (i >= n) return;

    float xi[N_IN_F];
    const float* xr = x + (size_t)i * N_IN_F;
#pragma unroll
    for (int k = 0; k < N_IN_F; ++k) xi[k] = xr[k];

    float di = rsqrtf((float)(deg[i] + 1));
    dis[i] = di;

    float* hs = hs1 + (size_t)i * N_HID;
#pragma unroll
    for (int f = 0; f < N_HID; ++f) {
        float h = 0.0f;
#pragma unroll
        for (int k = 0; k < N_IN_F; ++k) h = fmaf(xi[k], w[k * N_HID + f], h);
        hs[f] = h * di;
    }
}

// block per bucket: gather hs1[src] into padded LDS acc (ds_add), fused relu+W2 -> hs2
__global__ void __launch_bounds__(512)
k_aggB(const int* __restrict__ base, const int* __restrict__ binned,
       const float* __restrict__ hs1, const float* __restrict__ dis,
       const float* __restrict__ b1, const float* __restrict__ W2,
       float2* __restrict__ hs2, int n) {
    __shared__ float acc[NPB * 17];   // stride 17: spread ds_add banks
    int tid = threadIdx.x;
    for (int t = tid; t < NPB * 17; t += 512) acc[t] = 0.0f;
    __syncthreads();

    int b = blockIdx.x;
    int e0 = base[b], e1 = base[b + 1];
    int f = tid & 15;

    int e = e0 + (tid >> 4);                 // 32 groups of 16 lanes
    int p = (e < e1) ? binned[e] : 0;
    while (e < e1) {
        int en = e + 32;
        int pn = (en < e1) ? binned[en] : 0; // prefetch: hide binned latency under gather
        int s = p & SRC_MASK;
        int dl = p >> SRC_BITS;
        atomicAdd(&acc[dl * 17 + f], hs1[(size_t)s * N_HID + f]);
        p = pn;
        e = en;
    }
    __syncthreads();

    float b1f = b1[f];
    float w0 = W2[2 * f + 0];
    float w1 = W2[2 * f + 1];
    int node_base = b * NPB;
    for (int i0 = (tid >> 4); i0 < NPB; i0 += 32) {
        int g = node_base + i0;
        if (g >= n) break;
        float di = dis[g];
        float val = acc[i0 * 17 + f] + hs1[(size_t)g * N_HID + f];  // + self-loop
        float v = fmaxf(fmaf(di, val, b1f), 0.0f);
        float c0 = v * w0;
        float c1 = v * w1;
#pragma unroll
        for (int off = 8; off > 0; off >>= 1) {
            c0 += __shfl_xor(c0, off, 16);
            c1 += __shfl_xor(c1, off, 16);
        }
        if (f == 0) {
            float2 o;
            o.x = c0 * di;
            o.y = c1 * di;
            hs2[g] = o;
        }
    }
}

// block per bucket: gather hs2[src] into LDS acc, fused log_softmax -> out
__global__ void __launch_bounds__(512)
k_aggC(const int* __restrict__ base, const int* __restrict__ binned,
       const float2* __restrict__ hs2, const float* __restrict__ dis,
       const float* __restrict__ b2, float2* __restrict__ out, int n) {
    __shared__ float acc[NPB * 3];   // stride 3: spread ds_add banks
    int tid = threadIdx.x;
    for (int t = tid; t < NPB * 3; t += 512) acc[t] = 0.0f;
    __syncthreads();

    int b = blockIdx.x;
    int e0 = base[b], e1 = base[b + 1];

    int e = e0 + tid;
    int p = (e < e1) ? binned[e] : 0;
    while (e < e1) {
        int en = e + 512;
        int pn = (en < e1) ? binned[en] : 0;
        int s = p & SRC_MASK;
        int dl = p >> SRC_BITS;
        float2 v = hs2[s];
        atomicAdd(&acc[dl * 3 + 0], v.x);
        atomicAdd(&acc[dl * 3 + 1], v.y);
        p = pn;
        e = en;
    }
    __syncthreads();

    if (tid < NPB) {
        int g = b * NPB + tid;
        if (g < n) {
            float2 self = hs2[g];
            float di = dis[g];
            float a = fmaf(di, acc[tid * 3 + 0] + self.x, b2[0]);
            float bb = fmaf(di, acc[tid * 3 + 1] + self.y, b2[1]);
            float m = fmaxf(a, bb);
            float lse = m + logf(expf(a - m) + expf(bb - m));
            float2 o;
            o.x = a - lse;
            o.y = bb - lse;
            out[g] = o;
        }
    }
}

// ---------------- launch ----------------

extern "C" void kernel_launch(void* const* d_in, const int* in_sizes, int n_in,
                              void* d_out, int out_size, void* d_ws, size_t ws_size,
                              hipStream_t stream) {
    const float* x  = (const float*)d_in[0];
    const int*   ei = (const int*)d_in[1];
    const float* W1 = (const float*)d_in[2];
    const float* b1 = (const float*)d_in[3];
    const float* W2 = (const float*)d_in[4];
    const float* b2 = (const float*)d_in[5];
    float2* out = (float2*)d_out;

    const int n  = in_sizes[0] / N_IN_F;   // 200000
    const int ne = in_sizes[1] / 2;        // 6400000
    const int* src = ei;
    const int* dst = ei + ne;
    const int nb = (n + NPB - 1) / NPB;    // 782 <= 1024

    // workspace layout (ints/floats, 4B units)
    int* ws_i = (int*)d_ws;
    int* deg    = ws_i;                    // n
    int* bcnt   = deg + n;                 // 1024
    int* base   = bcnt + 1024;             // 1028 (nb+1 used)
    int* cursor = base + 1028;             // 1024
    int* binned = cursor + 1024;           // ne
    float* dis  = (float*)(binned + ne);   // n
    float* hs1  = dis + n;                 // n*16
    float2* hs2 = (float2*)(hs1 + (size_t)n * N_HID);  // n float2

    const int B = 256;

    k_zero_deg<<<dim3((n + B - 1) / B), dim3(B), 0, stream>>>(deg, n);
    k_deg<<<dim3((ne + B - 1) / B), dim3(B), 0, stream>>>(dst, deg, ne);
    k_bucket_cnt<<<dim3(nb), dim3(NPB), 0, stream>>>(deg, bcnt, n);
    k_scan<<<dim3(1), dim3(1024), 0, stream>>>(bcnt, base, cursor, nb, ne);
    k_bin<<<dim3((ne + EPB - 1) / EPB), dim3(B), 0, stream>>>(src, dst, cursor, binned, ne, nb);
    k_h1<<<dim3((n + B - 1) / B), dim3(B), 0, stream>>>(x, W1, deg, dis, hs1, n);
    k_aggB<<<dim3(nb), dim3(512), 0, stream>>>(base, binned, hs1, dis, b1, W2, hs2, n);
    k_aggC<<<dim3(nb), dim3(512), 0, stream>>>(base, binned, hs2, dis, b2, out, n);
}

// Round 4
// 931.121 us; speedup vs baseline: 1.2286x; 1.2286x over previous
//
#include <hip/hip_runtime.h>
#include <math.h>

#define N_IN_F 28
#define N_HID 16
#define NPB 256            // nodes per bucket (bucket = dst >> 8)
#define NB_MAX 1024        // capacity (782 actual)
#define EPB 8192           // edges per histogram/binning block
#define SRC_BITS 18
#define SRC_MASK ((1 << SRC_BITS) - 1)

// ---------------- build: bucket histogram -> scan -> bin ----------------

__global__ void k_zero_bcnt(int* __restrict__ bcnt) {
    bcnt[blockIdx.x * blockDim.x + threadIdx.x] = 0;
}

// chunked LDS histogram of dst>>8 -> global bucket counts
__global__ void __launch_bounds__(256)
k_bhist(const int* __restrict__ dst, int* __restrict__ bcnt, int ne, int nb) {
    __shared__ int hist[NB_MAX];
    int tid = threadIdx.x;
    for (int t = tid; t < nb; t += 256) hist[t] = 0;
    __syncthreads();
    int e0 = blockIdx.x * EPB;
    int e1 = min(e0 + EPB, ne);
    for (int e = e0 + tid; e < e1; e += 256) atomicAdd(&hist[dst[e] >> 8], 1);
    __syncthreads();
    for (int t = tid; t < nb; t += 256) {
        int c = hist[t];
        if (c) atomicAdd(&bcnt[t], c);
    }
}

// single block of 1024: exclusive scan of bcnt[nb] -> base, cursor
__global__ void k_scan(const int* __restrict__ bcnt, int* __restrict__ base,
                       int* __restrict__ cursor, int nb, int ne) {
    __shared__ int sm[1024];
    int v = (threadIdx.x < nb) ? bcnt[threadIdx.x] : 0;
    sm[threadIdx.x] = v;
    __syncthreads();
    for (int off = 1; off < 1024; off <<= 1) {
        int t = (threadIdx.x >= off) ? sm[threadIdx.x - off] : 0;
        __syncthreads();
        sm[threadIdx.x] += t;
        __syncthreads();
    }
    if (threadIdx.x < nb) {
        int ex = sm[threadIdx.x] - v;
        base[threadIdx.x] = ex;
        cursor[threadIdx.x] = ex;
    }
    if (threadIdx.x == 0) base[nb] = ne;
}

// bin edges by bucket: LDS count -> one global atomic per (block,bucket) -> scatter
__global__ void __launch_bounds__(256)
k_bin(const int* __restrict__ src, const int* __restrict__ dst,
      int* __restrict__ cursor, int* __restrict__ binned, int ne, int nb) {
    __shared__ int hist[NB_MAX];
    __shared__ int lc[NB_MAX];
    int tid = threadIdx.x;
    for (int t = tid; t < nb; t += 256) hist[t] = 0;
    __syncthreads();
    int e0 = blockIdx.x * EPB;
    int e1 = min(e0 + EPB, ne);
    for (int e = e0 + tid; e < e1; e += 256) atomicAdd(&hist[dst[e] >> 8], 1);
    __syncthreads();
    for (int t = tid; t < nb; t += 256) {
        int c = hist[t];
        lc[t] = c ? atomicAdd(&cursor[t], c) : 0;
    }
    __syncthreads();
    for (int e = e0 + tid; e < e1; e += 256) {
        int d = dst[e];
        int b = d >> 8;
        int pos = atomicAdd(&lc[b], 1);
        binned[pos] = src[e] | ((d & (NPB - 1)) << SRC_BITS);
    }
}

// block per bucket: degree via LDS histogram of binned -> dis = rsqrt(deg+1)
__global__ void __launch_bounds__(256)
k_deg_dis(const int* __restrict__ base, const int* __restrict__ binned,
          float* __restrict__ dis, int n) {
    __shared__ int cnt[NPB];
    int tid = threadIdx.x;
    cnt[tid] = 0;
    __syncthreads();
    int b = blockIdx.x;
    int e0 = base[b], e1 = base[b + 1];
    for (int e = e0 + tid; e < e1; e += 256) atomicAdd(&cnt[binned[e] >> SRC_BITS], 1);
    __syncthreads();
    int g = b * NPB + tid;
    if (g < n) dis[g] = rsqrtf((float)(cnt[tid] + 1));
}

// ---------------- compute ----------------

// per-node: hs1 = (x @ W1) * dis
__global__ void k_h1(const float* __restrict__ x, const float* __restrict__ W1,
                     const float* __restrict__ dis, float* __restrict__ hs1, int n) {
    __shared__ float w[N_IN_F * N_HID];
    for (int t = threadIdx.x; t < N_IN_F * N_HID; t += blockDim.x) w[t] = W1[t];
    __syncthreads();
    int i = blockIdx.x * blockDim.x + threadIdx.x;
    if (i >= n) return;

    float xi[N_IN_F];
    const float* xr = x + (size_t)i * N_IN_F;
#pragma unroll
    for (int k = 0; k < N_IN_F; ++k) xi[k] = xr[k];

    float di = dis[i];
    float* hs = hs1 + (size_t)i * N_HID;
#pragma unroll
    for (int f = 0; f < N_HID; ++f) {
        float h = 0.0f;
#pragma unroll
        for (int k = 0; k < N_IN_F; ++k) h = fmaf(xi[k], w[k * N_HID + f], h);
        hs[f] = h * di;
    }
}

// block per bucket, LANE PER EDGE: gather full 64B hs1 row (4x float4, high MLP),
// 16 ds_add into padded LDS acc; fused relu+W2 epilogue -> hs2
__global__ void __launch_bounds__(512)
k_aggB(const int* __restrict__ base, const int* __restrict__ binned,
       const float* __restrict__ hs1, const float* __restrict__ dis,
       const float* __restrict__ b1, const float* __restrict__ W2,
       float2* __restrict__ hs2, int n) {
    __shared__ float acc[NPB * 17];   // stride 17: spread banks
    int tid = threadIdx.x;
    for (int t = tid; t < NPB * 17; t += 512) acc[t] = 0.0f;
    __syncthreads();

    int b = blockIdx.x;
    int e0 = base[b], e1 = base[b + 1];

    for (int e = e0 + tid; e < e1; e += 512) {
        int p = binned[e];                       // coalesced
        int s = p & SRC_MASK;
        int dl = p >> SRC_BITS;
        const float4* row = (const float4*)(hs1 + (size_t)s * N_HID);
        float4 v0 = row[0];
        float4 v1 = row[1];
        float4 v2 = row[2];
        float4 v3 = row[3];
        float* a = &acc[dl * 17];
        atomicAdd(a + 0,  v0.x); atomicAdd(a + 1,  v0.y);
        atomicAdd(a + 2,  v0.z); atomicAdd(a + 3,  v0.w);
        atomicAdd(a + 4,  v1.x); atomicAdd(a + 5,  v1.y);
        atomicAdd(a + 6,  v1.z); atomicAdd(a + 7,  v1.w);
        atomicAdd(a + 8,  v2.x); atomicAdd(a + 9,  v2.y);
        atomicAdd(a + 10, v2.z); atomicAdd(a + 11, v2.w);
        atomicAdd(a + 12, v3.x); atomicAdd(a + 13, v3.y);
        atomicAdd(a + 14, v3.z); atomicAdd(a + 15, v3.w);
    }
    __syncthreads();

    int f = tid & 15;
    float b1f = b1[f];
    float w0 = W2[2 * f + 0];
    float w1 = W2[2 * f + 1];
    int node_base = b * NPB;
    for (int i0 = (tid >> 4); i0 < NPB; i0 += 32) {
        int g = node_base + i0;
        if (g >= n) break;
        float di = dis[g];
        float val = acc[i0 * 17 + f] + hs1[(size_t)g * N_HID + f];  // + self-loop
        float v = fmaxf(fmaf(di, val, b1f), 0.0f);
        float c0 = v * w0;
        float c1 = v * w1;
#pragma unroll
        for (int off = 8; off > 0; off >>= 1) {
            c0 += __shfl_xor(c0, off, 16);
            c1 += __shfl_xor(c1, off, 16);
        }
        if (f == 0) {
            float2 o;
            o.x = c0 * di;
            o.y = c1 * di;
            hs2[g] = o;
        }
    }
}

// block per bucket, lane per edge: gather hs2 (8B, L2-resident), LDS acc, fused log_softmax
__global__ void __launch_bounds__(512)
k_aggC(const int* __restrict__ base, const int* __restrict__ binned,
       const float2* __restrict__ hs2, const float* __restrict__ dis,
       const float* __restrict__ b2, float2* __restrict__ out, int n) {
    __shared__ float accx[NPB];
    __shared__ float accy[NPB];
    int tid = threadIdx.x;
    if (tid < NPB) { accx[tid] = 0.0f; accy[tid] = 0.0f; }
    __syncthreads();

    int b = blockIdx.x;
    int e0 = base[b], e1 = base[b + 1];

    for (int e = e0 + tid; e < e1; e += 512) {
        int p = binned[e];
        int s = p & SRC_MASK;
        int dl = p >> SRC_BITS;
        float2 v = hs2[s];
        atomicAdd(&accx[dl], v.x);
        atomicAdd(&accy[dl], v.y);
    }
    __syncthreads();

    if (tid < NPB) {
        int g = b * NPB + tid;
        if (g < n) {
            float2 self = hs2[g];
            float di = dis[g];
            float a = fmaf(di, accx[tid] + self.x, b2[0]);
            float c = fmaf(di, accy[tid] + self.y, b2[1]);
            float m = fmaxf(a, c);
            float lse = m + logf(expf(a - m) + expf(c - m));
            float2 o;
            o.x = a - lse;
            o.y = c - lse;
            out[g] = o;
        }
    }
}

// ---------------- launch ----------------

extern "C" void kernel_launch(void* const* d_in, const int* in_sizes, int n_in,
                              void* d_out, int out_size, void* d_ws, size_t ws_size,
                              hipStream_t stream) {
    const float* x  = (const float*)d_in[0];
    const int*   ei = (const int*)d_in[1];
    const float* W1 = (const float*)d_in[2];
    const float* b1 = (const float*)d_in[3];
    const float* W2 = (const float*)d_in[4];
    const float* b2 = (const float*)d_in[5];
    float2* out = (float2*)d_out;

    const int n  = in_sizes[0] / N_IN_F;   // 200000
    const int ne = in_sizes[1] / 2;        // 6400000
    const int* src = ei;
    const int* dst = ei + ne;
    const int nb = (n + NPB - 1) / NPB;    // 782 <= 1024

    // workspace layout (4B units; all offsets stay 16B-aligned)
    int* ws_i = (int*)d_ws;
    int* bcnt   = ws_i;                    // 1024
    int* base   = bcnt + 1024;             // 1028 (nb+1 used)
    int* cursor = base + 1028;             // 1024
    int* binned = cursor + 1024;           // ne
    float* dis  = (float*)(binned + ne);   // n
    float* hs1  = dis + n;                 // n*16
    float2* hs2 = (float2*)(hs1 + (size_t)n * N_HID);  // n float2

    const int B = 256;
    const int nchunk = (ne + EPB - 1) / EPB;  // 782

    k_zero_bcnt<<<dim3(4), dim3(B), 0, stream>>>(bcnt);
    k_bhist<<<dim3(nchunk), dim3(B), 0, stream>>>(dst, bcnt, ne, nb);
    k_scan<<<dim3(1), dim3(1024), 0, stream>>>(bcnt, base, cursor, nb, ne);
    k_bin<<<dim3(nchunk), dim3(B), 0, stream>>>(src, dst, cursor, binned, ne, nb);
    k_deg_dis<<<dim3(nb), dim3(B), 0, stream>>>(base, binned, dis, n);
    k_h1<<<dim3((n + B - 1) / B), dim3(B), 0, stream>>>(x, W1, dis, hs1, n);
    k_aggB<<<dim3(nb), dim3(512), 0, stream>>>(base, binned, hs1, dis, b1, W2, hs2, n);
    k_aggC<<<dim3(nb), dim3(512), 0, stream>>>(base, binned, hs2, dis, b2, out, n);
}

// Round 5
// 919.616 us; speedup vs baseline: 1.2439x; 1.0125x over previous
//
#include <hip/hip_runtime.h>
#include <math.h>

#define N_IN_F 28
#define N_HID 16
#define NPB 256              // nodes per dst-bucket (bucket = dst >> 8)
#define NB_MAX 1024          // dst-bucket capacity (782 actual)
#define EPB 16384            // edges per binning block (runs of ~21 edges/bucket)
#define SRC_BITS 18
#define SRC_MASK ((1 << SRC_BITS) - 1)
#define SRCB_SHIFT 14        // src-slice = 16384 nodes = 1MB of hs1 (L2-resident)
#define NSB_MAX 16           // 13 actual src-slices

// ---------------- build: bucket histogram -> scan -> bin -> in-bucket resort ----------------

__global__ void k_zero_bcnt(int* __restrict__ bcnt) {
    bcnt[blockIdx.x * blockDim.x + threadIdx.x] = 0;
}

// chunked LDS histogram of dst>>8 -> global bucket counts
__global__ void __launch_bounds__(256)
k_bhist(const int* __restrict__ dst, int* __restrict__ bcnt, int ne, int nb) {
    __shared__ int hist[NB_MAX];
    int tid = threadIdx.x;
    for (int t = tid; t < nb; t += 256) hist[t] = 0;
    __syncthreads();
    int e0 = blockIdx.x * EPB;
    int e1 = min(e0 + EPB, ne);
    for (int e = e0 + tid; e < e1; e += 256) atomicAdd(&hist[dst[e] >> 8], 1);
    __syncthreads();
    for (int t = tid; t < nb; t += 256) {
        int c = hist[t];
        if (c) atomicAdd(&bcnt[t], c);
    }
}

// single block of 1024: exclusive scan of bcnt[nb] -> base, cursor
__global__ void k_scan(const int* __restrict__ bcnt, int* __restrict__ base,
                       int* __restrict__ cursor, int nb, int ne) {
    __shared__ int sm[1024];
    int v = (threadIdx.x < nb) ? bcnt[threadIdx.x] : 0;
    sm[threadIdx.x] = v;
    __syncthreads();
    for (int off = 1; off < 1024; off <<= 1) {
        int t = (threadIdx.x >= off) ? sm[threadIdx.x - off] : 0;
        __syncthreads();
        sm[threadIdx.x] += t;
        __syncthreads();
    }
    if (threadIdx.x < nb) {
        int ex = sm[threadIdx.x] - v;
        base[threadIdx.x] = ex;
        cursor[threadIdx.x] = ex;
    }
    if (threadIdx.x == 0) base[nb] = ne;
}

// bin edges by dst-bucket: LDS count -> one global atomic per (block,bucket) -> scatter
__global__ void __launch_bounds__(256)
k_bin(const int* __restrict__ src, const int* __restrict__ dst,
      int* __restrict__ cursor, int* __restrict__ binned, int ne, int nb) {
    __shared__ int hist[NB_MAX];
    __shared__ int lc[NB_MAX];
    int tid = threadIdx.x;
    for (int t = tid; t < nb; t += 256) hist[t] = 0;
    __syncthreads();
    int e0 = blockIdx.x * EPB;
    int e1 = min(e0 + EPB, ne);
    for (int e = e0 + tid; e < e1; e += 256) atomicAdd(&hist[dst[e] >> 8], 1);
    __syncthreads();
    for (int t = tid; t < nb; t += 256) {
        int c = hist[t];
        lc[t] = c ? atomicAdd(&cursor[t], c) : 0;
    }
    __syncthreads();
    for (int e = e0 + tid; e < e1; e += 256) {
        int d = dst[e];
        int b = d >> 8;
        int pos = atomicAdd(&lc[b], 1);
        binned[pos] = src[e] | ((d & (NPB - 1)) << SRC_BITS);
    }
}

// block per dst-bucket: (a) degree -> dis (always), (b) re-sort bucket's edges
// by src-slice into binned2 (if do_sort) so aggB's gathers are L2-tiled.
__global__ void __launch_bounds__(256)
k_resort(const int* __restrict__ base, const int* __restrict__ binned,
         int* __restrict__ binned2, float* __restrict__ dis,
         int do_sort, int n) {
    __shared__ int cnt[NPB];
    __shared__ int h[NSB_MAX];
    __shared__ int cur[NSB_MAX];
    int tid = threadIdx.x;
    cnt[tid] = 0;
    if (tid < NSB_MAX) h[tid] = 0;
    __syncthreads();

    int b = blockIdx.x;
    int e0 = base[b], e1 = base[b + 1];

    for (int e = e0 + tid; e < e1; e += 256) {
        int p = binned[e];
        atomicAdd(&cnt[p >> SRC_BITS], 1);               // dst-local degree
        if (do_sort) atomicAdd(&h[(p & SRC_MASK) >> SRCB_SHIFT], 1);
    }
    __syncthreads();

    if (do_sort && tid == 0) {
        int run = e0;
#pragma unroll
        for (int s = 0; s < NSB_MAX; ++s) { cur[s] = run; run += h[s]; }
    }
    __syncthreads();

    if (do_sort) {
        for (int e = e0 + tid; e < e1; e += 256) {
            int p = binned[e];
            int pos = atomicAdd(&cur[(p & SRC_MASK) >> SRCB_SHIFT], 1);
            binned2[pos] = p;
        }
    }

    int g = b * NPB + tid;
    if (g < n) dis[g] = rsqrtf((float)(cnt[tid] + 1));   // +1 self-loop
}

// ---------------- compute ----------------

// per-node: hs1 = (x @ W1) * dis
__global__ void k_h1(const float* __restrict__ x, const float* __restrict__ W1,
                     const float* __restrict__ dis, float* __restrict__ hs1, int n) {
    __shared__ float w[N_IN_F * N_HID];
    for (int t = threadIdx.x; t < N_IN_F * N_HID; t += blockDim.x) w[t] = W1[t];
    __syncthreads();
    int i = blockIdx.x * blockDim.x + threadIdx.x;
    if (i >= n) return;

    float xi[N_IN_F];
    const float* xr = x + (size_t)i * N_IN_F;
#pragma unroll
    for (int k = 0; k < N_IN_F; ++k) xi[k] = xr[k];

    float di = dis[i];
    float* hs = hs1 + (size_t)i * N_HID;
#pragma unroll
    for (int f = 0; f < N_HID; ++f) {
        float h = 0.0f;
#pragma unroll
        for (int k = 0; k < N_IN_F; ++k) h = fmaf(xi[k], w[k * N_HID + f], h);
        hs[f] = h * di;
    }
}

// block per dst-bucket, lane per edge (src-slice-ordered): gather 64B hs1 row,
// 16 ds_add into padded LDS acc; fused relu+W2 epilogue -> hs2
__global__ void __launch_bounds__(512)
k_aggB(const int* __restrict__ base, const int* __restrict__ binned,
       const float* __restrict__ hs1, const float* __restrict__ dis,
       const float* __restrict__ b1, const float* __restrict__ W2,
       float2* __restrict__ hs2, int n) {
    __shared__ float acc[NPB * 17];   // stride 17: spread banks
    int tid = threadIdx.x;
    for (int t = tid; t < NPB * 17; t += 512) acc[t] = 0.0f;
    __syncthreads();

    int b = blockIdx.x;
    int e0 = base[b], e1 = base[b + 1];

    for (int e = e0 + tid; e < e1; e += 512) {
        int p = binned[e];                       // coalesced
        int s = p & SRC_MASK;
        int dl = p >> SRC_BITS;
        const float4* row = (const float4*)(hs1 + (size_t)s * N_HID);
        float4 v0 = row[0];
        float4 v1 = row[1];
        float4 v2 = row[2];
        float4 v3 = row[3];
        float* a = &acc[dl * 17];
        atomicAdd(a + 0,  v0.x); atomicAdd(a + 1,  v0.y);
        atomicAdd(a + 2,  v0.z); atomicAdd(a + 3,  v0.w);
        atomicAdd(a + 4,  v1.x); atomicAdd(a + 5,  v1.y);
        atomicAdd(a + 6,  v1.z); atomicAdd(a + 7,  v1.w);
        atomicAdd(a + 8,  v2.x); atomicAdd(a + 9,  v2.y);
        atomicAdd(a + 10, v2.z); atomicAdd(a + 11, v2.w);
        atomicAdd(a + 12, v3.x); atomicAdd(a + 13, v3.y);
        atomicAdd(a + 14, v3.z); atomicAdd(a + 15, v3.w);
    }
    __syncthreads();

    int f = tid & 15;
    float b1f = b1[f];
    float w0 = W2[2 * f + 0];
    float w1 = W2[2 * f + 1];
    int node_base = b * NPB;
    for (int i0 = (tid >> 4); i0 < NPB; i0 += 32) {
        int g = node_base + i0;
        if (g >= n) break;
        float di = dis[g];
        float val = acc[i0 * 17 + f] + hs1[(size_t)g * N_HID + f];  // + self-loop
        float v = fmaxf(fmaf(di, val, b1f), 0.0f);
        float c0 = v * w0;
        float c1 = v * w1;
#pragma unroll
        for (int off = 8; off > 0; off >>= 1) {
            c0 += __shfl_xor(c0, off, 16);
            c1 += __shfl_xor(c1, off, 16);
        }
        if (f == 0) {
            float2 o;
            o.x = c0 * di;
            o.y = c1 * di;
            hs2[g] = o;
        }
    }
}

// block per dst-bucket, lane per edge: gather hs2 (8B, L2-resident), LDS acc, fused log_softmax
__global__ void __launch_bounds__(512)
k_aggC(const int* __restrict__ base, const int* __restrict__ binned,
       const float2* __restrict__ hs2, const float* __restrict__ dis,
       const float* __restrict__ b2, float2* __restrict__ out, int n) {
    __shared__ float accx[NPB];
    __shared__ float accy[NPB];
    int tid = threadIdx.x;
    if (tid < NPB) { accx[tid] = 0.0f; accy[tid] = 0.0f; }
    __syncthreads();

    int b = blockIdx.x;
    int e0 = base[b], e1 = base[b + 1];

    for (int e = e0 + tid; e < e1; e += 512) {
        int p = binned[e];
        int s = p & SRC_MASK;
        int dl = p >> SRC_BITS;
        float2 v = hs2[s];
        atomicAdd(&accx[dl], v.x);
        atomicAdd(&accy[dl], v.y);
    }
    __syncthreads();

    if (tid < NPB) {
        int g = b * NPB + tid;
        if (g < n) {
            float2 self = hs2[g];
            float di = dis[g];
            float a = fmaf(di, accx[tid] + self.x, b2[0]);
            float c = fmaf(di, accy[tid] + self.y, b2[1]);
            float m = fmaxf(a, c);
            float lse = m + logf(expf(a - m) + expf(c - m));
            float2 o;
            o.x = a - lse;
            o.y = c - lse;
            out[g] = o;
        }
    }
}

// ---------------- launch ----------------

extern "C" void kernel_launch(void* const* d_in, const int* in_sizes, int n_in,
                              void* d_out, int out_size, void* d_ws, size_t ws_size,
                              hipStream_t stream) {
    const float* x  = (const float*)d_in[0];
    const int*   ei = (const int*)d_in[1];
    const float* W1 = (const float*)d_in[2];
    const float* b1 = (const float*)d_in[3];
    const float* W2 = (const float*)d_in[4];
    const float* b2 = (const float*)d_in[5];
    float2* out = (float2*)d_out;

    const int n  = in_sizes[0] / N_IN_F;   // 200000
    const int ne = in_sizes[1] / 2;        // 6400000
    const int* src = ei;
    const int* dst = ei + ne;
    const int nb = (n + NPB - 1) / NPB;    // 782 <= 1024

    // workspace layout (4B units; offsets stay 16B-aligned). binned2 goes LAST
    // so the base layout is valid even if ws can't hold it (do_sort=0 fallback).
    int* ws_i = (int*)d_ws;
    int* bcnt   = ws_i;                    // 1024
    int* base   = bcnt + 1024;             // 1028 (nb+1 used)
    int* cursor = base + 1028;             // 1024
    int* binned = cursor + 1024;           // ne
    float* dis  = (float*)(binned + ne);   // n
    float* hs1  = dis + n;                 // n*16
    float2* hs2 = (float2*)(hs1 + (size_t)n * N_HID);  // n float2
    int* binned2 = (int*)(hs2 + n);        // ne (optional)

    size_t need = ((size_t)3076 + (size_t)ne * 2 + (size_t)n * 19) * 4;
    int do_sort = (ws_size >= need) ? 1 : 0;
    const int* aggB_edges = do_sort ? binned2 : binned;

    const int B = 256;
    const int nchunk = (ne + EPB - 1) / EPB;  // 391

    k_zero_bcnt<<<dim3(4), dim3(B), 0, stream>>>(bcnt);
    k_bhist<<<dim3(nchunk), dim3(B), 0, stream>>>(dst, bcnt, ne, nb);
    k_scan<<<dim3(1), dim3(1024), 0, stream>>>(bcnt, base, cursor, nb, ne);
    k_bin<<<dim3(nchunk), dim3(B), 0, stream>>>(src, dst, cursor, binned, ne, nb);
    k_resort<<<dim3(nb), dim3(B), 0, stream>>>(base, binned, binned2, dis, do_sort, n);
    k_h1<<<dim3((n + B - 1) / B), dim3(B), 0, stream>>>(x, W1, dis, hs1, n);
    k_aggB<<<dim3(nb), dim3(512), 0, stream>>>(base, aggB_edges, hs1, dis, b1, W2, hs2, n);
    k_aggC<<<dim3(nb), dim3(512), 0, stream>>>(base, aggB_edges, hs2, dis, b2, out, n);
}

// Round 6
// 363.130 us; speedup vs baseline: 3.1502x; 2.5325x over previous
//
#include <hip/hip_runtime.h>
#include <math.h>

#define N_IN_F 28
#define N_HID 16
#define NPB 256              // nodes per dst-bucket (bucket = dst >> 8)
#define NB_MAX 1024          // dst-bucket capacity (782 actual)
#define EPB 16384            // edges per histogram/binning block
#define SRC_BITS 18
#define SRC_MASK ((1 << SRC_BITS) - 1)

// ---------------- build: bucket histogram -> scan -> bin -> per-bucket counting sort ----------------

__global__ void k_zero_bcnt(int* __restrict__ bcnt) {
    bcnt[blockIdx.x * blockDim.x + threadIdx.x] = 0;
}

// chunked LDS histogram of dst>>8 -> global bucket counts
__global__ void __launch_bounds__(256)
k_bhist(const int* __restrict__ dst, int* __restrict__ bcnt, int ne, int nb) {
    __shared__ int hist[NB_MAX];
    int tid = threadIdx.x;
    for (int t = tid; t < nb; t += 256) hist[t] = 0;
    __syncthreads();
    int e0 = blockIdx.x * EPB;
    int e1 = min(e0 + EPB, ne);
    for (int e = e0 + tid; e < e1; e += 256) atomicAdd(&hist[dst[e] >> 8], 1);
    __syncthreads();
    for (int t = tid; t < nb; t += 256) {
        int c = hist[t];
        if (c) atomicAdd(&bcnt[t], c);
    }
}

// single block of 1024: exclusive scan of bcnt[nb] -> base, cursor
__global__ void k_scan(const int* __restrict__ bcnt, int* __restrict__ base,
                       int* __restrict__ cursor, int nb, int ne) {
    __shared__ int sm[1024];
    int v = (threadIdx.x < nb) ? bcnt[threadIdx.x] : 0;
    sm[threadIdx.x] = v;
    __syncthreads();
    for (int off = 1; off < 1024; off <<= 1) {
        int t = (threadIdx.x >= off) ? sm[threadIdx.x - off] : 0;
        __syncthreads();
        sm[threadIdx.x] += t;
        __syncthreads();
    }
    if (threadIdx.x < nb) {
        int ex = sm[threadIdx.x] - v;
        base[threadIdx.x] = ex;
        cursor[threadIdx.x] = ex;
    }
    if (threadIdx.x == 0) base[nb] = ne;
}

// bin edges by dst-bucket: LDS count -> one global atomic per (block,bucket) -> scatter
// packed: src | dst_local << SRC_BITS
__global__ void __launch_bounds__(256)
k_bin(const int* __restrict__ src, const int* __restrict__ dst,
      int* __restrict__ cursor, int* __restrict__ binned, int ne, int nb) {
    __shared__ int hist[NB_MAX];
    __shared__ int lc[NB_MAX];
    int tid = threadIdx.x;
    for (int t = tid; t < nb; t += 256) hist[t] = 0;
    __syncthreads();
    int e0 = blockIdx.x * EPB;
    int e1 = min(e0 + EPB, ne);
    for (int e = e0 + tid; e < e1; e += 256) atomicAdd(&hist[dst[e] >> 8], 1);
    __syncthreads();
    for (int t = tid; t < nb; t += 256) {
        int c = hist[t];
        lc[t] = c ? atomicAdd(&cursor[t], c) : 0;
    }
    __syncthreads();
    for (int e = e0 + tid; e < e1; e += 256) {
        int d = dst[e];
        int b = d >> 8;
        int pos = atomicAdd(&lc[b], 1);
        binned[pos] = src[e] | ((d & (NPB - 1)) << SRC_BITS);
    }
}

// block per dst-bucket: counting sort by dst-local index -> node-contiguous edge list
// (binned2 holds plain src), plus row_start[] and dis[]. No global atomics.
__global__ void __launch_bounds__(256)
k_sort2(const int* __restrict__ base, const int* __restrict__ binned,
        int* __restrict__ binned2, int* __restrict__ row_start,
        float* __restrict__ dis, int n, int nb_total) {
    __shared__ int cnt[NPB];
    __shared__ int pos[NPB];
    __shared__ int cur[NPB];
    int tid = threadIdx.x;
    cnt[tid] = 0;
    __syncthreads();

    int b = blockIdx.x;
    int e0 = base[b], e1 = base[b + 1];

    for (int e = e0 + tid; e < e1; e += 256) atomicAdd(&cnt[binned[e] >> SRC_BITS], 1);
    __syncthreads();

    int v = cnt[tid];
    pos[tid] = v;
    __syncthreads();
    for (int off = 1; off < NPB; off <<= 1) {
        int t = (tid >= off) ? pos[tid - off] : 0;
        __syncthreads();
        pos[tid] += t;
        __syncthreads();
    }
    int excl = pos[tid] - v;           // exclusive prefix within bucket
    cur[tid] = e0 + excl;

    int g = b * NPB + tid;
    if (g < n) {
        row_start[g] = e0 + excl;
        dis[g] = rsqrtf((float)(v + 1));   // in-degree + self-loop
    }
    if (b == nb_total - 1 && tid == 0) row_start[n] = e1;
    __syncthreads();

    for (int e = e0 + tid; e < e1; e += 256) {
        int p = binned[e];
        int posn = atomicAdd(&cur[p >> SRC_BITS], 1);
        binned2[posn] = p & SRC_MASK;
    }
}

// ---------------- compute ----------------

// per-node: hs1 = (x @ W1) * dis
__global__ void k_h1(const float* __restrict__ x, const float* __restrict__ W1,
                     const float* __restrict__ dis, float* __restrict__ hs1, int n) {
    __shared__ float w[N_IN_F * N_HID];
    for (int t = threadIdx.x; t < N_IN_F * N_HID; t += blockDim.x) w[t] = W1[t];
    __syncthreads();
    int i = blockIdx.x * blockDim.x + threadIdx.x;
    if (i >= n) return;

    float xi[N_IN_F];
    const float* xr = x + (size_t)i * N_IN_F;
#pragma unroll
    for (int k = 0; k < N_IN_F; ++k) xi[k] = xr[k];

    float di = dis[i];
    float* hs = hs1 + (size_t)i * N_HID;
#pragma unroll
    for (int f = 0; f < N_HID; ++f) {
        float h = 0.0f;
#pragma unroll
        for (int k = 0; k < N_IN_F; ++k) h = fmaf(xi[k], w[k * N_HID + f], h);
        hs[f] = h * di;
    }
}

// 16 lanes per node: register-accumulation gather over node-contiguous edges,
// fused relu + W2 + cross-lane reduce -> hs2. NO LDS atomics.
__global__ void __launch_bounds__(256)
k_agg1(const int* __restrict__ row_start, const int* __restrict__ esrc,
       const float* __restrict__ hs1, const float* __restrict__ dis,
       const float* __restrict__ b1, const float* __restrict__ W2,
       float2* __restrict__ hs2, int n) {
    int t = blockIdx.x * blockDim.x + threadIdx.x;
    int node = t >> 4;
    int f = t & 15;
    if (node >= n) return;

    int beg = row_start[node];
    int end = row_start[node + 1];
    float acc = hs1[(size_t)node * N_HID + f];  // self-loop seed
    float a0 = 0.f, a1 = 0.f, a2 = 0.f, a3 = 0.f;
    int j = beg;
    for (; j + 4 <= end; j += 4) {
        int s0 = esrc[j];
        int s1 = esrc[j + 1];
        int s2 = esrc[j + 2];
        int s3 = esrc[j + 3];
        a0 += hs1[(size_t)s0 * N_HID + f];
        a1 += hs1[(size_t)s1 * N_HID + f];
        a2 += hs1[(size_t)s2 * N_HID + f];
        a3 += hs1[(size_t)s3 * N_HID + f];
    }
    for (; j < end; ++j) acc += hs1[(size_t)esrc[j] * N_HID + f];
    acc += (a0 + a1) + (a2 + a3);

    float di = dis[node];
    float v = fmaxf(fmaf(di, acc, b1[f]), 0.0f);
    float c0 = v * W2[2 * f + 0];
    float c1 = v * W2[2 * f + 1];
#pragma unroll
    for (int off = 8; off > 0; off >>= 1) {
        c0 += __shfl_xor(c0, off, 16);
        c1 += __shfl_xor(c1, off, 16);
    }
    if (f == 0) {
        float2 o;
        o.x = c0 * di;
        o.y = c1 * di;
        hs2[node] = o;
    }
}

// 4 lanes per node: gather-sum hs2 (float2, L2-resident) + fused log_softmax
__global__ void __launch_bounds__(256)
k_agg2(const int* __restrict__ row_start, const int* __restrict__ esrc,
       const float2* __restrict__ hs2, const float* __restrict__ dis,
       const float* __restrict__ b2, float2* __restrict__ out, int n) {
    int t = blockIdx.x * blockDim.x + threadIdx.x;
    int node = t >> 2;
    int l = t & 3;
    if (node >= n) return;

    int beg = row_start[node];
    int end = row_start[node + 1];
    float cx = 0.f, cy = 0.f;
    for (int j = beg + l; j < end; j += 4) {
        float2 v = hs2[esrc[j]];
        cx += v.x;
        cy += v.y;
    }
#pragma unroll
    for (int off = 2; off > 0; off >>= 1) {
        cx += __shfl_xor(cx, off, 4);
        cy += __shfl_xor(cy, off, 4);
    }
    if (l == 0) {
        float2 self = hs2[node];
        float di = dis[node];
        float a = fmaf(di, cx + self.x, b2[0]);
        float c = fmaf(di, cy + self.y, b2[1]);
        float m = fmaxf(a, c);
        float lse = m + logf(expf(a - m) + expf(c - m));
        float2 o;
        o.x = a - lse;
        o.y = c - lse;
        out[node] = o;
    }
}

// ---------------- launch ----------------

extern "C" void kernel_launch(void* const* d_in, const int* in_sizes, int n_in,
                              void* d_out, int out_size, void* d_ws, size_t ws_size,
                              hipStream_t stream) {
    const float* x  = (const float*)d_in[0];
    const int*   ei = (const int*)d_in[1];
    const float* W1 = (const float*)d_in[2];
    const float* b1 = (const float*)d_in[3];
    const float* W2 = (const float*)d_in[4];
    const float* b2 = (const float*)d_in[5];
    float2* out = (float2*)d_out;

    const int n  = in_sizes[0] / N_IN_F;   // 200000
    const int ne = in_sizes[1] / 2;        // 6400000
    const int* src = ei;
    const int* dst = ei + ne;
    const int nb = (n + NPB - 1) / NPB;    // 782 <= 1024

    // workspace layout (4B units). binned is DEAD after k_sort2, so hs1
    // (16n floats <= ne ints) aliases its space. Total ~54MB.
    int* ws_i = (int*)d_ws;
    int* bcnt      = ws_i;                      // 1024
    int* base      = bcnt + 1024;               // 1028 (nb+1 used)
    int* cursor    = base + 1028;               // 1024
    int* row_start = cursor + 1024;             // n+4
    float* dis     = (float*)(row_start + n + 4);  // n
    float2* hs2    = (float2*)(dis + n);        // n float2 (2n floats)
    int* binned2   = (int*)(hs2 + n);           // ne
    int* binned    = binned2 + ne;              // ne   } union with hs1
    float* hs1     = (float*)binned;            // 16n floats (16n <= ne)

    const int B = 256;
    const int nchunk = (ne + EPB - 1) / EPB;    // 391

    k_zero_bcnt<<<dim3(4), dim3(B), 0, stream>>>(bcnt);
    k_bhist<<<dim3(nchunk), dim3(B), 0, stream>>>(dst, bcnt, ne, nb);
    k_scan<<<dim3(1), dim3(1024), 0, stream>>>(bcnt, base, cursor, nb, ne);
    k_bin<<<dim3(nchunk), dim3(B), 0, stream>>>(src, dst, cursor, binned, ne, nb);
    k_sort2<<<dim3(nb), dim3(B), 0, stream>>>(base, binned, binned2, row_start, dis, n, nb);
    k_h1<<<dim3((n + B - 1) / B), dim3(B), 0, stream>>>(x, W1, dis, hs1, n);
    {
        long long tot = (long long)n * 16;
        k_agg1<<<dim3((unsigned)((tot + B - 1) / B)), dim3(B), 0, stream>>>(
            row_start, binned2, hs1, dis, b1, W2, hs2, n);
    }
    {
        long long tot = (long long)n * 4;
        k_agg2<<<dim3((unsigned)((tot + B - 1) / B)), dim3(B), 0, stream>>>(
            row_start, binned2, hs2, dis, b2, out, n);
    }
}

// Round 7
// 344.642 us; speedup vs baseline: 3.3192x; 1.0536x over previous
//
#include <hip/hip_runtime.h>
#include <hip/hip_fp16.h>
#include <math.h>

#define N_IN_F 28
#define N_HID 16
#define NPB 256              // nodes per dst-bucket (bucket = dst >> 8)
#define NB_MAX 1024          // dst-bucket capacity (782 actual)
#define EPB 8192             // edges per binning block (stage fits LDS)
#define SRC_BITS 18
#define SRC_MASK ((1 << SRC_BITS) - 1)

// ---------------- build: bucket histogram -> scan -> staged bin -> per-bucket counting sort ----------------

__global__ void k_zero_bcnt(int* __restrict__ bcnt) {
    bcnt[blockIdx.x * blockDim.x + threadIdx.x] = 0;
}

// chunked LDS histogram of dst>>8 -> global bucket counts
__global__ void __launch_bounds__(256)
k_bhist(const int* __restrict__ dst, int* __restrict__ bcnt, int ne, int nb) {
    __shared__ int hist[NB_MAX];
    int tid = threadIdx.x;
    for (int t = tid; t < nb; t += 256) hist[t] = 0;
    __syncthreads();
    int e0 = blockIdx.x * EPB;
    int e1 = min(e0 + EPB, ne);
    for (int e = e0 + tid; e < e1; e += 256) atomicAdd(&hist[dst[e] >> 8], 1);
    __syncthreads();
    for (int t = tid; t < nb; t += 256) {
        int c = hist[t];
        if (c) atomicAdd(&bcnt[t], c);
    }
}

// single block of 1024: exclusive scan of bcnt[nb] -> base, cursor
__global__ void k_scan(const int* __restrict__ bcnt, int* __restrict__ base,
                       int* __restrict__ cursor, int nb, int ne) {
    __shared__ int sm[1024];
    int v = (threadIdx.x < nb) ? bcnt[threadIdx.x] : 0;
    sm[threadIdx.x] = v;
    __syncthreads();
    for (int off = 1; off < 1024; off <<= 1) {
        int t = (threadIdx.x >= off) ? sm[threadIdx.x - off] : 0;
        __syncthreads();
        sm[threadIdx.x] += t;
        __syncthreads();
    }
    if (threadIdx.x < nb) {
        int ex = sm[threadIdx.x] - v;
        base[threadIdx.x] = ex;
        cursor[threadIdx.x] = ex;
    }
    if (threadIdx.x == 0) base[nb] = ne;
}

// staged bin: LDS counting-sort the chunk by bucket, then COALESCED write-out.
// packed: src | dst_local << SRC_BITS
__global__ void __launch_bounds__(256)
k_bin(const int* __restrict__ src, const int* __restrict__ dst,
      int* __restrict__ cursor, int* __restrict__ binned, int ne, int nb) {
    __shared__ int hist[NB_MAX];
    __shared__ int lbase[NB_MAX + 1];
    __shared__ int gdelta[NB_MAX];
    __shared__ int lcur[NB_MAX];
    __shared__ int ps[256];
    __shared__ int stage[EPB];
    int tid = threadIdx.x;
    int e0 = blockIdx.x * EPB;
    int csz = min(EPB, ne - e0);

    for (int t = tid; t < NB_MAX; t += 256) hist[t] = 0;
    __syncthreads();
    for (int i = tid; i < csz; i += 256) atomicAdd(&hist[dst[e0 + i] >> 8], 1);
    __syncthreads();

    // block-wide exclusive scan of hist[0..1023] (256 threads x 4)
    int s0 = hist[4 * tid + 0], s1 = hist[4 * tid + 1];
    int s2 = hist[4 * tid + 2], s3 = hist[4 * tid + 3];
    int sum = s0 + s1 + s2 + s3;
    ps[tid] = sum;
    __syncthreads();
    for (int off = 1; off < 256; off <<= 1) {
        int v = (tid >= off) ? ps[tid - off] : 0;
        __syncthreads();
        ps[tid] += v;
        __syncthreads();
    }
    int excl = ps[tid] - sum;
    lbase[4 * tid + 0] = excl;
    lbase[4 * tid + 1] = excl + s0;
    lbase[4 * tid + 2] = excl + s0 + s1;
    lbase[4 * tid + 3] = excl + s0 + s1 + s2;
    if (tid == 0) lbase[NB_MAX] = csz;
    __syncthreads();

    // reserve global ranges (one atomic per non-empty (block,bucket)); init local cursors
    for (int t = tid; t < nb; t += 256) {
        int c = hist[t];
        int g = c ? atomicAdd(&cursor[t], c) : 0;
        gdelta[t] = g - lbase[t];
        lcur[t] = lbase[t];
    }
    __syncthreads();

    // local scatter into LDS stage (bucket-sorted within chunk)
    for (int i = tid; i < csz; i += 256) {
        int d = dst[e0 + i];
        int b = d >> 8;
        int r = atomicAdd(&lcur[b], 1);
        stage[r] = src[e0 + i] | ((d & (NPB - 1)) << SRC_BITS);
    }
    __syncthreads();

    // coalesced write-out: consecutive lanes -> consecutive global positions per run
    for (int i = tid; i < csz; i += 256) {
        int lo = 0, hi = NB_MAX;                 // rightmost b with lbase[b] <= i
        while (hi - lo > 1) {
            int mid = (lo + hi) >> 1;
            if (lbase[mid] <= i) lo = mid; else hi = mid;
        }
        binned[gdelta[lo] + i] = stage[i];
    }
}

// block per dst-bucket: counting sort by dst-local index -> node-contiguous edge list
// (binned2 holds plain src), plus row_start[] and dis[]. No global atomics.
__global__ void __launch_bounds__(256)
k_sort2(const int* __restrict__ base, const int* __restrict__ binned,
        int* __restrict__ binned2, int* __restrict__ row_start,
        float* __restrict__ dis, int n, int nb_total) {
    __shared__ int cnt[NPB];
    __shared__ int pos[NPB];
    __shared__ int cur[NPB];
    int tid = threadIdx.x;
    cnt[tid] = 0;
    __syncthreads();

    int b = blockIdx.x;
    int e0 = base[b], e1 = base[b + 1];

    for (int e = e0 + tid; e < e1; e += 256) atomicAdd(&cnt[binned[e] >> SRC_BITS], 1);
    __syncthreads();

    int v = cnt[tid];
    pos[tid] = v;
    __syncthreads();
    for (int off = 1; off < NPB; off <<= 1) {
        int t = (tid >= off) ? pos[tid - off] : 0;
        __syncthreads();
        pos[tid] += t;
        __syncthreads();
    }
    int excl = pos[tid] - v;           // exclusive prefix within bucket
    cur[tid] = e0 + excl;

    int g = b * NPB + tid;
    if (g < n) {
        row_start[g] = e0 + excl;
        dis[g] = rsqrtf((float)(v + 1));   // in-degree + self-loop
    }
    if (b == nb_total - 1 && tid == 0) row_start[n] = e1;
    __syncthreads();

    for (int e = e0 + tid; e < e1; e += 256) {
        int p = binned[e];
        int posn = atomicAdd(&cur[p >> SRC_BITS], 1);
        binned2[posn] = p & SRC_MASK;
    }
}

// ---------------- compute ----------------

// per-node: hs1 = fp16( (x @ W1) * dis )
__global__ void k_h1(const float* __restrict__ x, const float* __restrict__ W1,
                     const float* __restrict__ dis, __half* __restrict__ hs1, int n) {
    __shared__ float w[N_IN_F * N_HID];
    for (int t = threadIdx.x; t < N_IN_F * N_HID; t += blockDim.x) w[t] = W1[t];
    __syncthreads();
    int i = blockIdx.x * blockDim.x + threadIdx.x;
    if (i >= n) return;

    float xi[N_IN_F];
    const float* xr = x + (size_t)i * N_IN_F;
#pragma unroll
    for (int k = 0; k < N_IN_F; ++k) xi[k] = xr[k];

    float di = dis[i];
    float hv[N_HID];
#pragma unroll
    for (int f = 0; f < N_HID; ++f) {
        float h = 0.0f;
#pragma unroll
        for (int k = 0; k < N_IN_F; ++k) h = fmaf(xi[k], w[k * N_HID + f], h);
        hv[f] = h * di;
    }
    __half2* hp = (__half2*)(hs1 + (size_t)i * N_HID);
#pragma unroll
    for (int f2 = 0; f2 < N_HID / 2; ++f2)
        hp[f2] = __floats2half2_rn(hv[2 * f2], hv[2 * f2 + 1]);
}

// 16 lanes per node: register-accumulation fp16 gather over node-contiguous edges,
// fused relu + W2 + cross-lane reduce -> hs2 (fp32). NO LDS atomics.
__global__ void __launch_bounds__(256)
k_agg1(const int* __restrict__ row_start, const int* __restrict__ esrc,
       const __half* __restrict__ hs1, const float* __restrict__ dis,
       const float* __restrict__ b1, const float* __restrict__ W2,
       float2* __restrict__ hs2, int n) {
    int t = blockIdx.x * blockDim.x + threadIdx.x;
    int node = t >> 4;
    int f = t & 15;
    if (node >= n) return;

    int beg = row_start[node];
    int end = row_start[node + 1];
    float acc = __half2float(hs1[(size_t)node * N_HID + f]);  // self-loop seed
    float a0 = 0.f, a1 = 0.f, a2 = 0.f, a3 = 0.f;
    int j = beg;
    for (; j + 4 <= end; j += 4) {
        int s0 = esrc[j];
        int s1 = esrc[j + 1];
        int s2 = esrc[j + 2];
        int s3 = esrc[j + 3];
        a0 += __half2float(hs1[(size_t)s0 * N_HID + f]);
        a1 += __half2float(hs1[(size_t)s1 * N_HID + f]);
        a2 += __half2float(hs1[(size_t)s2 * N_HID + f]);
        a3 += __half2float(hs1[(size_t)s3 * N_HID + f]);
    }
    for (; j < end; ++j) acc += __half2float(hs1[(size_t)esrc[j] * N_HID + f]);
    acc += (a0 + a1) + (a2 + a3);

    float di = dis[node];
    float v = fmaxf(fmaf(di, acc, b1[f]), 0.0f);
    float c0 = v * W2[2 * f + 0];
    float c1 = v * W2[2 * f + 1];
#pragma unroll
    for (int off = 8; off > 0; off >>= 1) {
        c0 += __shfl_xor(c0, off, 16);
        c1 += __shfl_xor(c1, off, 16);
    }
    if (f == 0) {
        float2 o;
        o.x = c0 * di;
        o.y = c1 * di;
        hs2[node] = o;
    }
}

// 4 lanes per node: gather-sum hs2 (float2, L2-resident) + fused log_softmax
__global__ void __launch_bounds__(256)
k_agg2(const int* __restrict__ row_start, const int* __restrict__ esrc,
       const float2* __restrict__ hs2, const float* __restrict__ dis,
       const float* __restrict__ b2, float2* __restrict__ out, int n) {
    int t = blockIdx.x * blockDim.x + threadIdx.x;
    int node = t >> 2;
    int l = t & 3;
    if (node >= n) return;

    int beg = row_start[node];
    int end = row_start[node + 1];
    float cx = 0.f, cy = 0.f;
    for (int j = beg + l; j < end; j += 4) {
        float2 v = hs2[esrc[j]];
        cx += v.x;
        cy += v.y;
    }
#pragma unroll
    for (int off = 2; off > 0; off >>= 1) {
        cx += __shfl_xor(cx, off, 4);
        cy += __shfl_xor(cy, off, 4);
    }
    if (l == 0) {
        float2 self = hs2[node];
        float di = dis[node];
        float a = fmaf(di, cx + self.x, b2[0]);
        float c = fmaf(di, cy + self.y, b2[1]);
        float m = fmaxf(a, c);
        float lse = m + logf(expf(a - m) + expf(c - m));
        float2 o;
        o.x = a - lse;
        o.y = c - lse;
        out[node] = o;
    }
}

// ---------------- launch ----------------

extern "C" void kernel_launch(void* const* d_in, const int* in_sizes, int n_in,
                              void* d_out, int out_size, void* d_ws, size_t ws_size,
                              hipStream_t stream) {
    const float* x  = (const float*)d_in[0];
    const int*   ei = (const int*)d_in[1];
    const float* W1 = (const float*)d_in[2];
    const float* b1 = (const float*)d_in[3];
    const float* W2 = (const float*)d_in[4];
    const float* b2 = (const float*)d_in[5];
    float2* out = (float2*)d_out;

    const int n  = in_sizes[0] / N_IN_F;   // 200000
    const int ne = in_sizes[1] / 2;        // 6400000
    const int* src = ei;
    const int* dst = ei + ne;
    const int nb = (n + NPB - 1) / NPB;    // 782 <= 1024

    // workspace layout (4B units). binned is DEAD after k_sort2, so hs1
    // (8n ints as half) aliases its space. Total ~54MB.
    int* ws_i = (int*)d_ws;
    int* bcnt      = ws_i;                      // 1024
    int* base      = bcnt + 1024;               // 1028 (nb+1 used)
    int* cursor    = base + 1028;               // 1024
    int* row_start = cursor + 1024;             // n+4
    float* dis     = (float*)(row_start + n + 4);  // n
    float2* hs2    = (float2*)(dis + n);        // n float2 (2n floats)
    int* binned2   = (int*)(hs2 + n);           // ne
    int* binned    = binned2 + ne;              // ne   } union with hs1
    __half* hs1    = (__half*)binned;           // 16n halfs (8n ints <= ne)

    const int B = 256;
    const int nchunk = (ne + EPB - 1) / EPB;    // 782

    k_zero_bcnt<<<dim3(4), dim3(B), 0, stream>>>(bcnt);
    k_bhist<<<dim3(nchunk), dim3(B), 0, stream>>>(dst, bcnt, ne, nb);
    k_scan<<<dim3(1), dim3(1024), 0, stream>>>(bcnt, base, cursor, nb, ne);
    k_bin<<<dim3(nchunk), dim3(B), 0, stream>>>(src, dst, cursor, binned, ne, nb);
    k_sort2<<<dim3(nb), dim3(B), 0, stream>>>(base, binned, binned2, row_start, dis, n, nb);
    k_h1<<<dim3((n + B - 1) / B), dim3(B), 0, stream>>>(x, W1, dis, hs1, n);
    {
        long long tot = (long long)n * 16;
        k_agg1<<<dim3((unsigned)((tot + B - 1) / B)), dim3(B), 0, stream>>>(
            row_start, binned2, hs1, dis, b1, W2, hs2, n);
    }
    {
        long long tot = (long long)n * 4;
        k_agg2<<<dim3((unsigned)((tot + B - 1) / B)), dim3(B), 0, stream>>>(
            row_start, binned2, hs2, dis, b2, out, n);
    }
}

// Round 8
// 315.971 us; speedup vs baseline: 3.6204x; 1.0907x over previous
//
#include <hip/hip_runtime.h>
#include <hip/hip_fp16.h>
#include <math.h>

#define N_IN_F 28
#define N_HID 16
#define NPB 256              // nodes per dst-bucket (bucket = dst >> 8)
#define NBK 1024             // bucket table size (782 actual)
#define EPB 4096             // edges per chunk (bhist/bin blocks)
#define SRC_BITS 18
#define SRC_MASK ((1 << SRC_BITS) - 1)

// ---------------- build: chunk histograms -> column scans -> positioned bin -> per-bucket sort ----------------

// chunk histogram of dst>>8, saved to global (u16, coalesced). No global atomics.
__global__ void __launch_bounds__(256)
k_bhist(const int* __restrict__ dst, unsigned short* __restrict__ chunk_hist, int ne) {
    __shared__ int hist[NBK];
    int tid = threadIdx.x;
    for (int t = tid; t < NBK; t += 256) hist[t] = 0;
    __syncthreads();
    int e0 = blockIdx.x * EPB;
    int e1 = min(e0 + EPB, ne);
    for (int e = e0 + tid; e < e1; e += 256) atomicAdd(&hist[dst[e] >> 8], 1);
    __syncthreads();
    unsigned short* ch = chunk_hist + (size_t)blockIdx.x * NBK;
    for (int t = tid; t < NBK; t += 256) ch[t] = (unsigned short)hist[t];
}

// 64 blocks x 16 buckets: per-bucket exclusive scan across chunks -> gdelta[chunk][bucket],
// plus per-bucket totals. Reads full 64B lines (16 u16 x ... contiguous buckets).
__global__ void __launch_bounds__(256)
k_colscan(const unsigned short* __restrict__ chunk_hist, int* __restrict__ gdelta,
          int* __restrict__ total, int nchunk) {
    __shared__ int p[16][17];
    int tid = threadIdx.x;
    int j = tid & 15;              // bucket lane within block's 16 buckets
    int g = tid >> 4;              // chunk-group
    int bkt = blockIdx.x * 16 + j;
    int cpg = (nchunk + 15) >> 4;
    int c0 = g * cpg, c1 = min(c0 + cpg, nchunk);

    int s = 0;
    for (int c = c0; c < c1; ++c) s += chunk_hist[(size_t)c * NBK + bkt];
    p[g][j] = s;
    __syncthreads();

    if (tid < 16) {                // serial scan over 16 groups for bucket tid
        int run = 0;
#pragma unroll
        for (int gg = 0; gg < 16; ++gg) { int t = p[gg][tid]; p[gg][tid] = run; run += t; }
        total[blockIdx.x * 16 + tid] = run;
    }
    __syncthreads();

    int run = p[g][j];
    for (int c = c0; c < c1; ++c) {
        int h = chunk_hist[(size_t)c * NBK + bkt];
        gdelta[(size_t)c * NBK + bkt] = run;
        run += h;
    }
}

// single block of 1024: exclusive scan of total -> base (+ sentinel)
__global__ void k_top(const int* __restrict__ total, int* __restrict__ base, int ne) {
    __shared__ int sm[NBK];
    int tid = threadIdx.x;
    int v = total[tid];
    sm[tid] = v;
    __syncthreads();
    for (int off = 1; off < NBK; off <<= 1) {
        int t = (tid >= off) ? sm[tid - off] : 0;
        __syncthreads();
        sm[tid] += t;
        __syncthreads();
    }
    base[tid] = sm[tid] - v;
    if (tid == 0) base[NBK] = ne;
}

// positioned bin: cursors fully precomputed; one LDS atomic + one store per edge.
__global__ void __launch_bounds__(256)
k_bin(const int* __restrict__ src, const int* __restrict__ dst,
      const int* __restrict__ gdelta, const int* __restrict__ base,
      int* __restrict__ binned, int ne) {
    __shared__ int lcur[NBK];
    int tid = threadIdx.x;
    const int* gd = gdelta + (size_t)blockIdx.x * NBK;
    for (int t = tid; t < NBK; t += 256) lcur[t] = gd[t] + base[t];
    __syncthreads();
    int e0 = blockIdx.x * EPB;
    int e1 = min(e0 + EPB, ne);
    for (int e = e0 + tid; e < e1; e += 256) {
        int d = dst[e];
        int b = d >> 8;
        int r = atomicAdd(&lcur[b], 1);
        binned[r] = src[e] | ((d & (NPB - 1)) << SRC_BITS);
    }
}

// block per dst-bucket: counting sort by dst-local index -> node-contiguous edge list
// (binned2 holds plain src), plus row_start[] and dis[]. No global atomics.
__global__ void __launch_bounds__(256)
k_sort2(const int* __restrict__ base, const int* __restrict__ binned,
        int* __restrict__ binned2, int* __restrict__ row_start,
        float* __restrict__ dis, int n, int nb_total) {
    __shared__ int cnt[NPB];
    __shared__ int pos[NPB];
    __shared__ int cur[NPB];
    int tid = threadIdx.x;
    cnt[tid] = 0;
    __syncthreads();

    int b = blockIdx.x;
    int e0 = base[b], e1 = base[b + 1];

    for (int e = e0 + tid; e < e1; e += 256) atomicAdd(&cnt[binned[e] >> SRC_BITS], 1);
    __syncthreads();

    int v = cnt[tid];
    pos[tid] = v;
    __syncthreads();
    for (int off = 1; off < NPB; off <<= 1) {
        int t = (tid >= off) ? pos[tid - off] : 0;
        __syncthreads();
        pos[tid] += t;
        __syncthreads();
    }
    int excl = pos[tid] - v;           // exclusive prefix within bucket
    cur[tid] = e0 + excl;

    int g = b * NPB + tid;
    if (g < n) {
        row_start[g] = e0 + excl;
        dis[g] = rsqrtf((float)(v + 1));   // in-degree + self-loop
    }
    if (b == nb_total - 1 && tid == 0) row_start[n] = e1;
    __syncthreads();

    for (int e = e0 + tid; e < e1; e += 256) {
        int p = binned[e];
        int posn = atomicAdd(&cur[p >> SRC_BITS], 1);
        binned2[posn] = p & SRC_MASK;
    }
}

// ---------------- compute ----------------

// per-node: hs1 = fp16( (x @ W1) * dis ); x rows loaded as float4 (112B stride, 16B aligned)
__global__ void k_h1(const float* __restrict__ x, const float* __restrict__ W1,
                     const float* __restrict__ dis, __half* __restrict__ hs1, int n) {
    __shared__ float w[N_IN_F * N_HID];
    for (int t = threadIdx.x; t < N_IN_F * N_HID; t += blockDim.x) w[t] = W1[t];
    __syncthreads();
    int i = blockIdx.x * blockDim.x + threadIdx.x;
    if (i >= n) return;

    float xi[N_IN_F];
    const float4* xr = (const float4*)(x + (size_t)i * N_IN_F);
#pragma unroll
    for (int q = 0; q < N_IN_F / 4; ++q) {
        float4 v = xr[q];
        xi[4 * q + 0] = v.x; xi[4 * q + 1] = v.y;
        xi[4 * q + 2] = v.z; xi[4 * q + 3] = v.w;
    }

    float di = dis[i];
    float hv[N_HID];
#pragma unroll
    for (int f = 0; f < N_HID; ++f) {
        float h = 0.0f;
#pragma unroll
        for (int k = 0; k < N_IN_F; ++k) h = fmaf(xi[k], w[k * N_HID + f], h);
        hv[f] = h * di;
    }
    __half2* hp = (__half2*)(hs1 + (size_t)i * N_HID);
#pragma unroll
    for (int f2 = 0; f2 < N_HID / 2; ++f2)
        hp[f2] = __floats2half2_rn(hv[2 * f2], hv[2 * f2 + 1]);
}

// 16 lanes per node: register-accumulation fp16 gather over node-contiguous edges,
// fused relu + W2 + cross-lane reduce -> hs2 (fp32). NO LDS atomics.
__global__ void __launch_bounds__(256)
k_agg1(const int* __restrict__ row_start, const int* __restrict__ esrc,
       const __half* __restrict__ hs1, const float* __restrict__ dis,
       const float* __restrict__ b1, const float* __restrict__ W2,
       float2* __restrict__ hs2, int n) {
    int t = blockIdx.x * blockDim.x + threadIdx.x;
    int node = t >> 4;
    int f = t & 15;
    if (node >= n) return;

    int beg = row_start[node];
    int end = row_start[node + 1];
    float acc = __half2float(hs1[(size_t)node * N_HID + f]);  // self-loop seed
    float a0 = 0.f, a1 = 0.f, a2 = 0.f, a3 = 0.f;
    int j = beg;
    for (; j + 4 <= end; j += 4) {
        int s0 = esrc[j];
        int s1 = esrc[j + 1];
        int s2 = esrc[j + 2];
        int s3 = esrc[j + 3];
        a0 += __half2float(hs1[(size_t)s0 * N_HID + f]);
        a1 += __half2float(hs1[(size_t)s1 * N_HID + f]);
        a2 += __half2float(hs1[(size_t)s2 * N_HID + f]);
        a3 += __half2float(hs1[(size_t)s3 * N_HID + f]);
    }
    for (; j < end; ++j) acc += __half2float(hs1[(size_t)esrc[j] * N_HID + f]);
    acc += (a0 + a1) + (a2 + a3);

    float di = dis[node];
    float v = fmaxf(fmaf(di, acc, b1[f]), 0.0f);
    float c0 = v * W2[2 * f + 0];
    float c1 = v * W2[2 * f + 1];
#pragma unroll
    for (int off = 8; off > 0; off >>= 1) {
        c0 += __shfl_xor(c0, off, 16);
        c1 += __shfl_xor(c1, off, 16);
    }
    if (f == 0) {
        float2 o;
        o.x = c0 * di;
        o.y = c1 * di;
        hs2[node] = o;
    }
}

// 4 lanes per node: gather-sum hs2 (float2, L2-resident) + fused log_softmax
__global__ void __launch_bounds__(256)
k_agg2(const int* __restrict__ row_start, const int* __restrict__ esrc,
       const float2* __restrict__ hs2, const float* __restrict__ dis,
       const float* __restrict__ b2, float2* __restrict__ out, int n) {
    int t = blockIdx.x * blockDim.x + threadIdx.x;
    int node = t >> 2;
    int l = t & 3;
    if (node >= n) return;

    int beg = row_start[node];
    int end = row_start[node + 1];
    float cx = 0.f, cy = 0.f;
    for (int j = beg + l; j < end; j += 4) {
        float2 v = hs2[esrc[j]];
        cx += v.x;
        cy += v.y;
    }
#pragma unroll
    for (int off = 2; off > 0; off >>= 1) {
        cx += __shfl_xor(cx, off, 4);
        cy += __shfl_xor(cy, off, 4);
    }
    if (l == 0) {
        float2 self = hs2[node];
        float di = dis[node];
        float a = fmaf(di, cx + self.x, b2[0]);
        float c = fmaf(di, cy + self.y, b2[1]);
        float m = fmaxf(a, c);
        float lse = m + logf(expf(a - m) + expf(c - m));
        float2 o;
        o.x = a - lse;
        o.y = c - lse;
        out[node] = o;
    }
}

// ---------------- launch ----------------

extern "C" void kernel_launch(void* const* d_in, const int* in_sizes, int n_in,
                              void* d_out, int out_size, void* d_ws, size_t ws_size,
                              hipStream_t stream) {
    const float* x  = (const float*)d_in[0];
    const int*   ei = (const int*)d_in[1];
    const float* W1 = (const float*)d_in[2];
    const float* b1 = (const float*)d_in[3];
    const float* W2 = (const float*)d_in[4];
    const float* b2 = (const float*)d_in[5];
    float2* out = (float2*)d_out;

    const int n  = in_sizes[0] / N_IN_F;   // 200000
    const int ne = in_sizes[1] / 2;        // 6400000
    const int* src = ei;
    const int* dst = ei + ne;
    const int nb = (n + NPB - 1) / NPB;    // 782 <= 1024
    const int nchunk = (ne + EPB - 1) / EPB;  // 1563

    // workspace layout (4B units). Aliasing (ordering-safe):
    //   chunk_hist (u16, nchunk*1024) lives in binned's region  (dead before k_bin writes binned)
    //   gdelta (nchunk*1024 ints)     lives in binned2's region (dead before k_sort2 writes binned2)
    //   hs1 (16n halfs = 8n ints)     lives in binned's region  (dead after k_sort2)
    int* ws_i = (int*)d_ws;
    int* total     = ws_i;                      // 1024
    int* base      = total + 1024;              // 1028 (NBK+1 used)
    int* row_start = base + 1028;               // n+4
    float* dis     = (float*)(row_start + n + 4);  // n
    float2* hs2    = (float2*)(dis + n);        // n float2 (2n floats)
    int* binned2   = (int*)(hs2 + n);           // ne
    int* binned    = binned2 + ne;              // ne
    int* gdelta    = binned2;                                  // alias (nchunk*1024 <= ne)
    unsigned short* chunk_hist = (unsigned short*)binned;      // alias (nchunk*1024 u16 <= ne*2)
    __half* hs1    = (__half*)binned;                          // alias

    const int B = 256;

    k_bhist<<<dim3(nchunk), dim3(B), 0, stream>>>(dst, chunk_hist, ne);
    k_colscan<<<dim3(NBK / 16), dim3(B), 0, stream>>>(chunk_hist, gdelta, total, nchunk);
    k_top<<<dim3(1), dim3(NBK), 0, stream>>>(total, base, ne);
    k_bin<<<dim3(nchunk), dim3(B), 0, stream>>>(src, dst, gdelta, base, binned, ne);
    k_sort2<<<dim3(nb), dim3(B), 0, stream>>>(base, binned, binned2, row_start, dis, n, nb);
    k_h1<<<dim3((n + B - 1) / B), dim3(B), 0, stream>>>(x, W1, dis, hs1, n);
    {
        long long tot = (long long)n * 16;
        k_agg1<<<dim3((unsigned)((tot + B - 1) / B)), dim3(B), 0, stream>>>(
            row_start, binned2, hs1, dis, b1, W2, hs2, n);
    }
    {
        long long tot = (long long)n * 4;
        k_agg2<<<dim3((unsigned)((tot + B - 1) / B)), dim3(B), 0, stream>>>(
            row_start, binned2, hs2, dis, b2, out, n);
    }
}

// Round 9
// 274.190 us; speedup vs baseline: 4.1721x; 1.1524x over previous
//
#include <hip/hip_runtime.h>
#include <hip/hip_fp16.h>
#include <math.h>

#define N_IN_F 28
#define N_HID 16
#define NPB 256              // nodes per dst-bucket (bucket = dst >> 8)
#define NBK 1024             // bucket table size (782 actual)
#define EPB 4096             // edges per chunk (bhist/bin blocks)
#define SRC_BITS 18
#define SRC_MASK ((1 << SRC_BITS) - 1)

// ---------------- build: chunk histograms -> column scans -> staged bin -> per-bucket sort ----------------

// chunk histogram of dst>>8, saved to global (u16, coalesced). No global atomics.
__global__ void __launch_bounds__(256)
k_bhist(const int* __restrict__ dst, unsigned short* __restrict__ chunk_hist, int ne) {
    __shared__ int hist[NBK];
    int tid = threadIdx.x;
    for (int t = tid; t < NBK; t += 256) hist[t] = 0;
    __syncthreads();
    int e0 = blockIdx.x * EPB;
    int e1 = min(e0 + EPB, ne);
    for (int e = e0 + tid; e < e1; e += 256) atomicAdd(&hist[dst[e] >> 8], 1);
    __syncthreads();
    unsigned short* ch = chunk_hist + (size_t)blockIdx.x * NBK;
    for (int t = tid; t < NBK; t += 256) ch[t] = (unsigned short)hist[t];
}

// 64 blocks x 16 buckets: per-bucket exclusive scan across chunks -> gdelta[chunk][bucket],
// plus per-bucket totals.
__global__ void __launch_bounds__(256)
k_colscan(const unsigned short* __restrict__ chunk_hist, int* __restrict__ gdelta,
          int* __restrict__ total, int nchunk) {
    __shared__ int p[16][17];
    int tid = threadIdx.x;
    int j = tid & 15;              // bucket lane within block's 16 buckets
    int g = tid >> 4;              // chunk-group
    int bkt = blockIdx.x * 16 + j;
    int cpg = (nchunk + 15) >> 4;
    int c0 = g * cpg, c1 = min(c0 + cpg, nchunk);

    int s = 0;
    for (int c = c0; c < c1; ++c) s += chunk_hist[(size_t)c * NBK + bkt];
    p[g][j] = s;
    __syncthreads();

    if (tid < 16) {                // serial scan over 16 groups for bucket tid
        int run = 0;
#pragma unroll
        for (int gg = 0; gg < 16; ++gg) { int t = p[gg][tid]; p[gg][tid] = run; run += t; }
        total[blockIdx.x * 16 + tid] = run;
    }
    __syncthreads();

    int run = p[g][j];
    for (int c = c0; c < c1; ++c) {
        int h = chunk_hist[(size_t)c * NBK + bkt];
        gdelta[(size_t)c * NBK + bkt] = run;
        run += h;
    }
}

// single block of 1024: exclusive scan of total -> base (+ sentinel)
__global__ void k_top(const int* __restrict__ total, int* __restrict__ base, int ne) {
    __shared__ int sm[NBK];
    int tid = threadIdx.x;
    int v = total[tid];
    sm[tid] = v;
    __syncthreads();
    for (int off = 1; off < NBK; off <<= 1) {
        int t = (tid >= off) ? sm[tid - off] : 0;
        __syncthreads();
        sm[tid] += t;
        __syncthreads();
    }
    base[tid] = sm[tid] - v;
    if (tid == 0) base[NBK] = ne;
}

// staged bin: positions fully precomputed (no global atomics, no re-histogram).
// LDS counting-sort the chunk by bucket, then coalesced write-out with O(1) lookup.
__global__ void __launch_bounds__(256)
k_bin(const int* __restrict__ src, const int* __restrict__ dst,
      const unsigned short* __restrict__ chunk_hist, const int* __restrict__ gdelta,
      const int* __restrict__ base, int* __restrict__ binned, int ne) {
    __shared__ int lbase[NBK];
    __shared__ int gpos[NBK];
    __shared__ int lcur[NBK];
    __shared__ int ps[256];
    __shared__ int stage[EPB];
    __shared__ unsigned short sbid[EPB];
    int tid = threadIdx.x;
    int chunk = blockIdx.x;
    const unsigned short* ch = chunk_hist + (size_t)chunk * NBK;
    const int* gd = gdelta + (size_t)chunk * NBK;

    // load this chunk's hist row (4/thread) and block-scan -> lbase
    ushort4 hq = ((const ushort4*)ch)[tid];
    int h0 = hq.x, h1v = hq.y, h2 = hq.z, h3 = hq.w;
    int sum = h0 + h1v + h2 + h3;
    ps[tid] = sum;
    __syncthreads();
    for (int off = 1; off < 256; off <<= 1) {
        int v = (tid >= off) ? ps[tid - off] : 0;
        __syncthreads();
        ps[tid] += v;
        __syncthreads();
    }
    int excl = ps[tid] - sum;
    int lb0 = excl, lb1 = excl + h0, lb2 = excl + h0 + h1v, lb3 = excl + h0 + h1v + h2;
    lbase[4 * tid + 0] = lb0;
    lbase[4 * tid + 1] = lb1;
    lbase[4 * tid + 2] = lb2;
    lbase[4 * tid + 3] = lb3;
    int4 gdq = ((const int4*)gd)[tid];
    int4 bq  = ((const int4*)base)[tid];
    gpos[4 * tid + 0] = bq.x + gdq.x - lb0;
    gpos[4 * tid + 1] = bq.y + gdq.y - lb1;
    gpos[4 * tid + 2] = bq.z + gdq.z - lb2;
    gpos[4 * tid + 3] = bq.w + gdq.w - lb3;
    lcur[4 * tid + 0] = lb0;
    lcur[4 * tid + 1] = lb1;
    lcur[4 * tid + 2] = lb2;
    lcur[4 * tid + 3] = lb3;
    __syncthreads();

    int e0 = chunk * EPB;
    int csz = min(EPB, ne - e0);

    // local scatter into LDS stage (bucket-sorted within chunk)
    for (int i = tid; i < csz; i += 256) {
        int d = dst[e0 + i];
        int b = d >> 8;
        int r = atomicAdd(&lcur[b], 1);
        stage[r] = src[e0 + i] | ((d & (NPB - 1)) << SRC_BITS);
        sbid[r] = (unsigned short)b;
    }
    __syncthreads();

    // coalesced write-out: consecutive lanes -> consecutive global positions per run
    for (int i = tid; i < csz; i += 256) {
        int b = sbid[i];
        binned[gpos[b] + i] = stage[i];
    }
}

// block per dst-bucket: counting sort by dst-local index -> node-contiguous edge list
// (binned2 holds plain src), plus row_start[] and dis[]. No global atomics.
__global__ void __launch_bounds__(256)
k_sort2(const int* __restrict__ base, const int* __restrict__ binned,
        int* __restrict__ binned2, int* __restrict__ row_start,
        float* __restrict__ dis, int n, int nb_total) {
    __shared__ int cnt[NPB];
    __shared__ int pos[NPB];
    __shared__ int cur[NPB];
    int tid = threadIdx.x;
    cnt[tid] = 0;
    __syncthreads();

    int b = blockIdx.x;
    int e0 = base[b], e1 = base[b + 1];

    for (int e = e0 + tid; e < e1; e += 256) atomicAdd(&cnt[binned[e] >> SRC_BITS], 1);
    __syncthreads();

    int v = cnt[tid];
    pos[tid] = v;
    __syncthreads();
    for (int off = 1; off < NPB; off <<= 1) {
        int t = (tid >= off) ? pos[tid - off] : 0;
        __syncthreads();
        pos[tid] += t;
        __syncthreads();
    }
    int excl = pos[tid] - v;           // exclusive prefix within bucket
    cur[tid] = e0 + excl;

    int g = b * NPB + tid;
    if (g < n) {
        row_start[g] = e0 + excl;
        dis[g] = rsqrtf((float)(v + 1));   // in-degree + self-loop
    }
    if (b == nb_total - 1 && tid == 0) row_start[n] = e1;
    __syncthreads();

    for (int e = e0 + tid; e < e1; e += 256) {
        int p = binned[e];
        int posn = atomicAdd(&cur[p >> SRC_BITS], 1);
        binned2[posn] = p & SRC_MASK;
    }
}

// ---------------- compute ----------------

// per-node: hs1 = fp16( (x @ W1) * dis ); x rows loaded as float4
__global__ void k_h1(const float* __restrict__ x, const float* __restrict__ W1,
                     const float* __restrict__ dis, __half* __restrict__ hs1, int n) {
    __shared__ float w[N_IN_F * N_HID];
    for (int t = threadIdx.x; t < N_IN_F * N_HID; t += blockDim.x) w[t] = W1[t];
    __syncthreads();
    int i = blockIdx.x * blockDim.x + threadIdx.x;
    if (i >= n) return;

    float xi[N_IN_F];
    const float4* xr = (const float4*)(x + (size_t)i * N_IN_F);
#pragma unroll
    for (int q = 0; q < N_IN_F / 4; ++q) {
        float4 v = xr[q];
        xi[4 * q + 0] = v.x; xi[4 * q + 1] = v.y;
        xi[4 * q + 2] = v.z; xi[4 * q + 3] = v.w;
    }

    float di = dis[i];
    float hv[N_HID];
#pragma unroll
    for (int f = 0; f < N_HID; ++f) {
        float h = 0.0f;
#pragma unroll
        for (int k = 0; k < N_IN_F; ++k) h = fmaf(xi[k], w[k * N_HID + f], h);
        hv[f] = h * di;
    }
    __half2* hp = (__half2*)(hs1 + (size_t)i * N_HID);
#pragma unroll
    for (int f2 = 0; f2 < N_HID / 2; ++f2)
        hp[f2] = __floats2half2_rn(hv[2 * f2], hv[2 * f2 + 1]);
}

// 16 lanes per node: register-accumulation fp16 gather over node-contiguous edges,
// fused relu + W2 + cross-lane reduce -> hs2 (fp32). NO LDS atomics.
__global__ void __launch_bounds__(256)
k_agg1(const int* __restrict__ row_start, const int* __restrict__ esrc,
       const __half* __restrict__ hs1, const float* __restrict__ dis,
       const float* __restrict__ b1, const float* __restrict__ W2,
       float2* __restrict__ hs2, int n) {
    int t = blockIdx.x * blockDim.x + threadIdx.x;
    int node = t >> 4;
    int f = t & 15;
    if (node >= n) return;

    int beg = row_start[node];
    int end = row_start[node + 1];
    float acc = __half2float(hs1[(size_t)node * N_HID + f]);  // self-loop seed
    float a0 = 0.f, a1 = 0.f, a2 = 0.f, a3 = 0.f;
    int j = beg;
    for (; j + 4 <= end; j += 4) {
        int s0 = esrc[j];
        int s1 = esrc[j + 1];
        int s2 = esrc[j + 2];
        int s3 = esrc[j + 3];
        a0 += __half2float(hs1[(size_t)s0 * N_HID + f]);
        a1 += __half2float(hs1[(size_t)s1 * N_HID + f]);
        a2 += __half2float(hs1[(size_t)s2 * N_HID + f]);
        a3 += __half2float(hs1[(size_t)s3 * N_HID + f]);
    }
    for (; j < end; ++j) acc += __half2float(hs1[(size_t)esrc[j] * N_HID + f]);
    acc += (a0 + a1) + (a2 + a3);

    float di = dis[node];
    float v = fmaxf(fmaf(di, acc, b1[f]), 0.0f);
    float c0 = v * W2[2 * f + 0];
    float c1 = v * W2[2 * f + 1];
#pragma unroll
    for (int off = 8; off > 0; off >>= 1) {
        c0 += __shfl_xor(c0, off, 16);
        c1 += __shfl_xor(c1, off, 16);
    }
    if (f == 0) {
        float2 o;
        o.x = c0 * di;
        o.y = c1 * di;
        hs2[node] = o;
    }
}

// 4 lanes per node: gather-sum hs2 (float2, L2-resident) + fused log_softmax
__global__ void __launch_bounds__(256)
k_agg2(const int* __restrict__ row_start, const int* __restrict__ esrc,
       const float2* __restrict__ hs2, const float* __restrict__ dis,
       const float* __restrict__ b2, float2* __restrict__ out, int n) {
    int t = blockIdx.x * blockDim.x + threadIdx.x;
    int node = t >> 2;
    int l = t & 3;
    if (node >= n) return;

    int beg = row_start[node];
    int end = row_start[node + 1];
    float cx = 0.f, cy = 0.f;
    for (int j = beg + l; j < end; j += 4) {
        float2 v = hs2[esrc[j]];
        cx += v.x;
        cy += v.y;
    }
#pragma unroll
    for (int off = 2; off > 0; off >>= 1) {
        cx += __shfl_xor(cx, off, 4);
        cy += __shfl_xor(cy, off, 4);
    }
    if (l == 0) {
        float2 self = hs2[node];
        float di = dis[node];
        float a = fmaf(di, cx + self.x, b2[0]);
        float c = fmaf(di, cy + self.y, b2[1]);
        float m = fmaxf(a, c);
        float lse = m + logf(expf(a - m) + expf(c - m));
        float2 o;
        o.x = a - lse;
        o.y = c - lse;
        out[node] = o;
    }
}

// ---------------- launch ----------------

extern "C" void kernel_launch(void* const* d_in, const int* in_sizes, int n_in,
                              void* d_out, int out_size, void* d_ws, size_t ws_size,
                              hipStream_t stream) {
    const float* x  = (const float*)d_in[0];
    const int*   ei = (const int*)d_in[1];
    const float* W1 = (const float*)d_in[2];
    const float* b1 = (const float*)d_in[3];
    const float* W2 = (const float*)d_in[4];
    const float* b2 = (const float*)d_in[5];
    float2* out = (float2*)d_out;

    const int n  = in_sizes[0] / N_IN_F;   // 200000
    const int ne = in_sizes[1] / 2;        // 6400000
    const int* src = ei;
    const int* dst = ei + ne;
    const int nb = (n + NPB - 1) / NPB;    // 782 <= 1024
    const int nchunk = (ne + EPB - 1) / EPB;  // 1563

    // workspace layout (4B units). Aliasing (ordering-safe):
    //   chunk_hist is a STANDALONE region (k_bin reads it while writing binned)
    //   gdelta (nchunk*NBK ints) aliases binned2 (dead before k_sort2 writes binned2)
    //   hs1 (16n halfs = 8n ints) aliases binned (dead after k_sort2)
    int* ws_i = (int*)d_ws;
    int* total     = ws_i;                      // 1024
    int* base      = total + 1024;              // 1028 (NBK+1 used)
    int* row_start = base + 1028;               // n+4
    float* dis     = (float*)(row_start + n + 4);  // n
    float2* hs2    = (float2*)(dis + n);        // n float2 (2n floats)
    unsigned short* chunk_hist = (unsigned short*)(hs2 + n);  // nchunk*NBK u16
    int* binned2   = (int*)chunk_hist + ((size_t)nchunk * NBK + 1) / 2;  // ne
    int* binned    = binned2 + ne;              // ne
    int* gdelta    = binned2;                   // alias (nchunk*NBK ints <= ne)
    __half* hs1    = (__half*)binned;           // alias

    const int B = 256;

    k_bhist<<<dim3(nchunk), dim3(B), 0, stream>>>(dst, chunk_hist, ne);
    k_colscan<<<dim3(NBK / 16), dim3(B), 0, stream>>>(chunk_hist, gdelta, total, nchunk);
    k_top<<<dim3(1), dim3(NBK), 0, stream>>>(total, base, ne);
    k_bin<<<dim3(nchunk), dim3(B), 0, stream>>>(src, dst, chunk_hist, gdelta, base, binned, ne);
    k_sort2<<<dim3(nb), dim3(B), 0, stream>>>(base, binned, binned2, row_start, dis, n, nb);
    k_h1<<<dim3((n + B - 1) / B), dim3(B), 0, stream>>>(x, W1, dis, hs1, n);
    {
        long long tot = (long long)n * 16;
        k_agg1<<<dim3((unsigned)((tot + B - 1) / B)), dim3(B), 0, stream>>>(
            row_start, binned2, hs1, dis, b1, W2, hs2, n);
    }
    {
        long long tot = (long long)n * 4;
        k_agg2<<<dim3((unsigned)((tot + B - 1) / B)), dim3(B), 0, stream>>>(
            row_start, binned2, hs2, dis, b2, out, n);
    }
}

// Round 10
// 272.931 us; speedup vs baseline: 4.1913x; 1.0046x over previous
//
#include <hip/hip_runtime.h>
#include <hip/hip_fp16.h>
#include <math.h>

#define N_IN_F 28
#define N_HID 16
#define NPB 256              // nodes per dst-bucket (bucket = dst >> 8)
#define NBK 1024             // bucket table size (782 actual)
#define EPB 4096             // edges per chunk (bhist/bin blocks)
#define SRC_BITS 18
#define SRC_MASK ((1 << SRC_BITS) - 1)

// ---------------- build: chunk histograms -> column scans -> staged bin -> per-bucket sort+h1 ----------------

// chunk histogram of dst>>8, saved to global (u16, coalesced). No global atomics.
__global__ void __launch_bounds__(256)
k_bhist(const int* __restrict__ dst, unsigned short* __restrict__ chunk_hist, int ne) {
    __shared__ int hist[NBK];
    int tid = threadIdx.x;
    for (int t = tid; t < NBK; t += 256) hist[t] = 0;
    __syncthreads();
    int e0 = blockIdx.x * EPB;
    int e1 = min(e0 + EPB, ne);
    for (int e = e0 + tid; e < e1; e += 256) atomicAdd(&hist[dst[e] >> 8], 1);
    __syncthreads();
    unsigned short* ch = chunk_hist + (size_t)blockIdx.x * NBK;
    for (int t = tid; t < NBK; t += 256) ch[t] = (unsigned short)hist[t];
}

// 64 blocks x 16 buckets: per-bucket exclusive scan across chunks -> gdelta[chunk][bucket],
// plus per-bucket totals.
__global__ void __launch_bounds__(256)
k_colscan(const unsigned short* __restrict__ chunk_hist, int* __restrict__ gdelta,
          int* __restrict__ total, int nchunk) {
    __shared__ int p[16][17];
    int tid = threadIdx.x;
    int j = tid & 15;              // bucket lane within block's 16 buckets
    int g = tid >> 4;              // chunk-group
    int bkt = blockIdx.x * 16 + j;
    int cpg = (nchunk + 15) >> 4;
    int c0 = g * cpg, c1 = min(c0 + cpg, nchunk);

    int s = 0;
    for (int c = c0; c < c1; ++c) s += chunk_hist[(size_t)c * NBK + bkt];
    p[g][j] = s;
    __syncthreads();

    if (tid < 16) {                // serial scan over 16 groups for bucket tid
        int run = 0;
#pragma unroll
        for (int gg = 0; gg < 16; ++gg) { int t = p[gg][tid]; p[gg][tid] = run; run += t; }
        total[blockIdx.x * 16 + tid] = run;
    }
    __syncthreads();

    int run = p[g][j];
    for (int c = c0; c < c1; ++c) {
        int h = chunk_hist[(size_t)c * NBK + bkt];
        gdelta[(size_t)c * NBK + bkt] = run;
        run += h;
    }
}

// single block of 1024: exclusive scan of total -> base (+ sentinel)
__global__ void k_top(const int* __restrict__ total, int* __restrict__ base, int ne) {
    __shared__ int sm[NBK];
    int tid = threadIdx.x;
    int v = total[tid];
    sm[tid] = v;
    __syncthreads();
    for (int off = 1; off < NBK; off <<= 1) {
        int t = (tid >= off) ? sm[tid - off] : 0;
        __syncthreads();
        sm[tid] += t;
        __syncthreads();
    }
    base[tid] = sm[tid] - v;
    if (tid == 0) base[NBK] = ne;
}

// staged bin: positions fully precomputed (no global atomics, no re-histogram).
// LDS counting-sort the chunk by bucket (int2 stage), coalesced write-out, O(1) lookup.
__global__ void __launch_bounds__(256)
k_bin(const int* __restrict__ src, const int* __restrict__ dst,
      const unsigned short* __restrict__ chunk_hist, const int* __restrict__ gdelta,
      const int* __restrict__ base, int* __restrict__ binned, int ne) {
    __shared__ int gpos[NBK];
    __shared__ int lcur[NBK];
    __shared__ int ps[256];
    __shared__ int2 stage[EPB];
    int tid = threadIdx.x;
    int chunk = blockIdx.x;
    const unsigned short* ch = chunk_hist + (size_t)chunk * NBK;
    const int* gd = gdelta + (size_t)chunk * NBK;

    // load this chunk's hist row (4/thread) and block-scan -> local bases
    ushort4 hq = ((const ushort4*)ch)[tid];
    int h0 = hq.x, h1v = hq.y, h2 = hq.z, h3 = hq.w;
    int sum = h0 + h1v + h2 + h3;
    ps[tid] = sum;
    __syncthreads();
    for (int off = 1; off < 256; off <<= 1) {
        int v = (tid >= off) ? ps[tid - off] : 0;
        __syncthreads();
        ps[tid] += v;
        __syncthreads();
    }
    int excl = ps[tid] - sum;
    int lb0 = excl, lb1 = excl + h0, lb2 = lb1 + h1v, lb3 = lb2 + h2;
    int4 gdq = ((const int4*)gd)[tid];
    int4 bq  = ((const int4*)base)[tid];
    gpos[4 * tid + 0] = bq.x + gdq.x - lb0;
    gpos[4 * tid + 1] = bq.y + gdq.y - lb1;
    gpos[4 * tid + 2] = bq.z + gdq.z - lb2;
    gpos[4 * tid + 3] = bq.w + gdq.w - lb3;
    lcur[4 * tid + 0] = lb0;
    lcur[4 * tid + 1] = lb1;
    lcur[4 * tid + 2] = lb2;
    lcur[4 * tid + 3] = lb3;
    __syncthreads();

    int e0 = chunk * EPB;
    int csz = min(EPB, ne - e0);

    // local scatter into LDS stage (bucket-sorted within chunk), 8B per edge
    for (int i = tid; i < csz; i += 256) {
        int d = dst[e0 + i];
        int b = d >> 8;
        int r = atomicAdd(&lcur[b], 1);
        int2 sv;
        sv.x = src[e0 + i] | ((d & (NPB - 1)) << SRC_BITS);
        sv.y = b;
        stage[r] = sv;
    }
    __syncthreads();

    // coalesced write-out: consecutive lanes -> consecutive global positions per run
    for (int i = tid; i < csz; i += 256) {
        int2 sv = stage[i];
        binned[gpos[sv.y] + i] = sv.x;
    }
}

// block per dst-bucket: counting sort by dst-local index -> node-contiguous edge list
// (binned2 = plain src), row_start[], dis[]; FUSED h1: hs1 = fp16((x@W1)*dis).
__global__ void __launch_bounds__(256)
k_sort2(const int* __restrict__ base, const int* __restrict__ binned,
        int* __restrict__ binned2, int* __restrict__ row_start,
        float* __restrict__ dis, const float* __restrict__ x,
        const float* __restrict__ W1, __half* __restrict__ hs1,
        int n, int nb_total) {
    __shared__ int cnt[NPB];
    __shared__ int pos[NPB];
    __shared__ int cur[NPB];
    __shared__ float w[N_IN_F * N_HID];
    int tid = threadIdx.x;
    cnt[tid] = 0;
    for (int t = tid; t < N_IN_F * N_HID; t += 256) w[t] = W1[t];
    __syncthreads();

    int b = blockIdx.x;
    int e0 = base[b], e1 = base[b + 1];

    for (int e = e0 + tid; e < e1; e += 256) atomicAdd(&cnt[binned[e] >> SRC_BITS], 1);
    __syncthreads();

    int v = cnt[tid];
    pos[tid] = v;
    __syncthreads();
    for (int off = 1; off < NPB; off <<= 1) {
        int t = (tid >= off) ? pos[tid - off] : 0;
        __syncthreads();
        pos[tid] += t;
        __syncthreads();
    }
    int excl = pos[tid] - v;           // exclusive prefix within bucket
    cur[tid] = e0 + excl;

    int g = b * NPB + tid;
    float di = rsqrtf((float)(v + 1));
    if (g < n) {
        row_start[g] = e0 + excl;
        dis[g] = di;                   // in-degree + self-loop
    }
    if (b == nb_total - 1 && tid == 0) row_start[n] = e1;
    __syncthreads();

    for (int e = e0 + tid; e < e1; e += 256) {
        int p = binned[e];
        int posn = atomicAdd(&cur[p >> SRC_BITS], 1);
        binned2[posn] = p & SRC_MASK;
    }

    // fused h1 for this bucket's 256 nodes (thread = node)
    if (g < n) {
        float xi[N_IN_F];
        const float4* xr = (const float4*)(x + (size_t)g * N_IN_F);
#pragma unroll
        for (int q = 0; q < N_IN_F / 4; ++q) {
            float4 vv = xr[q];
            xi[4 * q + 0] = vv.x; xi[4 * q + 1] = vv.y;
            xi[4 * q + 2] = vv.z; xi[4 * q + 3] = vv.w;
        }
        __half2 hp[N_HID / 2];
#pragma unroll
        for (int f2 = 0; f2 < N_HID / 2; ++f2) {
            float ha = 0.0f, hb = 0.0f;
#pragma unroll
            for (int k = 0; k < N_IN_F; ++k) {
                ha = fmaf(xi[k], w[k * N_HID + 2 * f2], ha);
                hb = fmaf(xi[k], w[k * N_HID + 2 * f2 + 1], hb);
            }
            hp[f2] = __floats2half2_rn(ha * di, hb * di);
        }
        int4* dstp = (int4*)(hs1 + (size_t)g * N_HID);
        dstp[0] = *(const int4*)&hp[0];
        dstp[1] = *(const int4*)&hp[4];
    }
}

// ---------------- compute ----------------

// 8 lanes per node (half2 per lane): register-accumulation gather, 8-edge unroll,
// fused relu + W2 + cross-lane reduce -> hs2 (fp32). NO LDS atomics.
__global__ void __launch_bounds__(256)
k_agg1(const int* __restrict__ row_start, const int* __restrict__ esrc,
       const __half2* __restrict__ hs1, const float* __restrict__ dis,
       const float* __restrict__ b1, const float* __restrict__ W2,
       float2* __restrict__ hs2, int n) {
    int t = blockIdx.x * blockDim.x + threadIdx.x;
    int node = t >> 3;
    int f2 = t & 7;
    if (node >= n) return;

    int beg = row_start[node];
    int end = row_start[node + 1];
    const __half2* H = hs1 + f2;           // H[s*8] = hs1[s*8 + f2]

    float2 sl = __half22float2(H[node * 8]);   // self-loop seed
    float ax = sl.x, ay = sl.y;
    float a0x = 0.f, a0y = 0.f, a1x = 0.f, a1y = 0.f;
    float a2x = 0.f, a2y = 0.f, a3x = 0.f, a3y = 0.f;
    int j = beg;
    for (; j + 8 <= end; j += 8) {
        int s0 = esrc[j],     s1 = esrc[j + 1], s2 = esrc[j + 2], s3 = esrc[j + 3];
        int s4 = esrc[j + 4], s5 = esrc[j + 5], s6 = esrc[j + 6], s7 = esrc[j + 7];
        float2 v0 = __half22float2(H[s0 * 8]);
        float2 v1 = __half22float2(H[s1 * 8]);
        float2 v2 = __half22float2(H[s2 * 8]);
        float2 v3 = __half22float2(H[s3 * 8]);
        float2 v4 = __half22float2(H[s4 * 8]);
        float2 v5 = __half22float2(H[s5 * 8]);
        float2 v6 = __half22float2(H[s6 * 8]);
        float2 v7 = __half22float2(H[s7 * 8]);
        a0x += v0.x; a0y += v0.y; a1x += v1.x; a1y += v1.y;
        a2x += v2.x; a2y += v2.y; a3x += v3.x; a3y += v3.y;
        a0x += v4.x; a0y += v4.y; a1x += v5.x; a1y += v5.y;
        a2x += v6.x; a2y += v6.y; a3x += v7.x; a3y += v7.y;
    }
    for (; j + 4 <= end; j += 4) {
        int s0 = esrc[j], s1 = esrc[j + 1], s2 = esrc[j + 2], s3 = esrc[j + 3];
        float2 v0 = __half22float2(H[s0 * 8]);
        float2 v1 = __half22float2(H[s1 * 8]);
        float2 v2 = __half22float2(H[s2 * 8]);
        float2 v3 = __half22float2(H[s3 * 8]);
        a0x += v0.x; a0y += v0.y; a1x += v1.x; a1y += v1.y;
        a2x += v2.x; a2y += v2.y; a3x += v3.x; a3y += v3.y;
    }
    for (; j < end; ++j) {
        float2 v0 = __half22float2(H[esrc[j] * 8]);
        ax += v0.x; ay += v0.y;
    }
    ax += (a0x + a1x) + (a2x + a3x);
    ay += (a0y + a1y) + (a2y + a3y);

    float di = dis[node];
    float vx = fmaxf(fmaf(di, ax, b1[2 * f2 + 0]), 0.0f);
    float vy = fmaxf(fmaf(di, ay, b1[2 * f2 + 1]), 0.0f);
    float c0 = vx * W2[4 * f2 + 0] + vy * W2[4 * f2 + 2];
    float c1 = vx * W2[4 * f2 + 1] + vy * W2[4 * f2 + 3];
#pragma unroll
    for (int off = 4; off > 0; off >>= 1) {
        c0 += __shfl_xor(c0, off, 8);
        c1 += __shfl_xor(c1, off, 8);
    }
    if (f2 == 0) {
        float2 o;
        o.x = c0 * di;
        o.y = c1 * di;
        hs2[node] = o;
    }
}

// 4 lanes per node: gather-sum hs2 (float2, L2-resident) + fused log_softmax
__global__ void __launch_bounds__(256)
k_agg2(const int* __restrict__ row_start, const int* __restrict__ esrc,
       const float2* __restrict__ hs2, const float* __restrict__ dis,
       const float* __restrict__ b2, float2* __restrict__ out, int n) {
    int t = blockIdx.x * blockDim.x + threadIdx.x;
    int node = t >> 2;
    int l = t & 3;
    if (node >= n) return;

    int beg = row_start[node];
    int end = row_start[node + 1];
    float cx = 0.f, cy = 0.f;
    for (int j = beg + l; j < end; j += 4) {
        float2 v = hs2[esrc[j]];
        cx += v.x;
        cy += v.y;
    }
#pragma unroll
    for (int off = 2; off > 0; off >>= 1) {
        cx += __shfl_xor(cx, off, 4);
        cy += __shfl_xor(cy, off, 4);
    }
    if (l == 0) {
        float2 self = hs2[node];
        float di = dis[node];
        float a = fmaf(di, cx + self.x, b2[0]);
        float c = fmaf(di, cy + self.y, b2[1]);
        float m = fmaxf(a, c);
        float lse = m + logf(expf(a - m) + expf(c - m));
        float2 o;
        o.x = a - lse;
        o.y = c - lse;
        out[node] = o;
    }
}

// ---------------- launch ----------------

extern "C" void kernel_launch(void* const* d_in, const int* in_sizes, int n_in,
                              void* d_out, int out_size, void* d_ws, size_t ws_size,
                              hipStream_t stream) {
    const float* x  = (const float*)d_in[0];
    const int*   ei = (const int*)d_in[1];
    const float* W1 = (const float*)d_in[2];
    const float* b1 = (const float*)d_in[3];
    const float* W2 = (const float*)d_in[4];
    const float* b2 = (const float*)d_in[5];
    float2* out = (float2*)d_out;

    const int n  = in_sizes[0] / N_IN_F;   // 200000
    const int ne = in_sizes[1] / 2;        // 6400000
    const int* src = ei;
    const int* dst = ei + ne;
    const int nb = (n + NPB - 1) / NPB;    // 782 <= 1024
    const int nchunk = (ne + EPB - 1) / EPB;  // 1563

    // workspace layout (4B units), total ~64MB. Aliasing (ordering-safe):
    //   gdelta (nchunk*NBK ints) aliases binned2 (dead before k_sort2 writes binned2)
    //   chunk_hist, hs1 are STANDALONE (hs1 written by k_sort2 while binned still live elsewhere)
    int* ws_i = (int*)d_ws;
    int* total     = ws_i;                      // 1024
    int* base      = total + 1024;              // 1028 (NBK+1 used)
    int* row_start = base + 1028;               // n+4
    float* dis     = (float*)(row_start + n + 4);  // n
    float2* hs2    = (float2*)(dis + n);        // n float2 (2n floats)
    __half* hs1    = (__half*)(hs2 + n);        // 16n halfs = 8n ints
    unsigned short* chunk_hist = (unsigned short*)((int*)hs1 + 8 * (size_t)n);  // nchunk*NBK u16
    int* binned2   = (int*)chunk_hist + ((size_t)nchunk * NBK + 1) / 2;  // ne
    int* binned    = binned2 + ne;              // ne
    int* gdelta    = binned2;                   // alias (nchunk*NBK ints <= ne)

    const int B = 256;

    k_bhist<<<dim3(nchunk), dim3(B), 0, stream>>>(dst, chunk_hist, ne);
    k_colscan<<<dim3(NBK / 16), dim3(B), 0, stream>>>(chunk_hist, gdelta, total, nchunk);
    k_top<<<dim3(1), dim3(NBK), 0, stream>>>(total, base, ne);
    k_bin<<<dim3(nchunk), dim3(B), 0, stream>>>(src, dst, chunk_hist, gdelta, base, binned, ne);
    k_sort2<<<dim3(nb), dim3(B), 0, stream>>>(base, binned, binned2, row_start, dis,
                                              x, W1, hs1, n, nb);
    {
        long long tot = (long long)n * 8;
        k_agg1<<<dim3((unsigned)((tot + B - 1) / B)), dim3(B), 0, stream>>>(
            row_start, binned2, (const __half2*)hs1, dis, b1, W2, hs2, n);
    }
    {
        long long tot = (long long)n * 4;
        k_agg2<<<dim3((unsigned)((tot + B - 1) / B)), dim3(B), 0, stream>>>(
            row_start, binned2, hs2, dis, b2, out, n);
    }
}

// Round 11
// 226.441 us; speedup vs baseline: 5.0518x; 1.2053x over previous
//
#include <hip/hip_runtime.h>
#include <hip/hip_fp16.h>
#include <math.h>

#define N_IN_F 28
#define N_HID 16
#define NPB 256              // nodes per dst-bucket (bucket = dst >> 8)
#define NBK 1024             // bucket table size (782 actual)
#define EPB 4096             // edges per chunk (bhist/bin blocks)
#define SRC_BITS 18
#define SRC_MASK ((1 << SRC_BITS) - 1)
#define STAGE_CAP 10240      // LDS stage entries for k_sort2 (bucket mean 8192, sigma ~90)

// ---------------- build: chunk histograms -> column scans -> staged bin -> staged sort+h1 ----------------

// chunk histogram of dst>>8, saved to global (u16, coalesced). No global atomics.
__global__ void __launch_bounds__(256)
k_bhist(const int* __restrict__ dst, unsigned short* __restrict__ chunk_hist, int ne) {
    __shared__ int hist[NBK];
    int tid = threadIdx.x;
    for (int t = tid; t < NBK; t += 256) hist[t] = 0;
    __syncthreads();
    int e0 = blockIdx.x * EPB;
    int e1 = min(e0 + EPB, ne);
    for (int e = e0 + tid; e < e1; e += 256) atomicAdd(&hist[dst[e] >> 8], 1);
    __syncthreads();
    unsigned short* ch = chunk_hist + (size_t)blockIdx.x * NBK;
    for (int t = tid; t < NBK; t += 256) ch[t] = (unsigned short)hist[t];
}

// 64 blocks x 16 buckets: per-bucket exclusive scan across chunks -> gdelta[chunk][bucket],
// plus per-bucket totals.
__global__ void __launch_bounds__(256)
k_colscan(const unsigned short* __restrict__ chunk_hist, int* __restrict__ gdelta,
          int* __restrict__ total, int nchunk) {
    __shared__ int p[16][17];
    int tid = threadIdx.x;
    int j = tid & 15;              // bucket lane within block's 16 buckets
    int g = tid >> 4;              // chunk-group
    int bkt = blockIdx.x * 16 + j;
    int cpg = (nchunk + 15) >> 4;
    int c0 = g * cpg, c1 = min(c0 + cpg, nchunk);

    int s = 0;
    for (int c = c0; c < c1; ++c) s += chunk_hist[(size_t)c * NBK + bkt];
    p[g][j] = s;
    __syncthreads();

    if (tid < 16) {                // serial scan over 16 groups for bucket tid
        int run = 0;
#pragma unroll
        for (int gg = 0; gg < 16; ++gg) { int t = p[gg][tid]; p[gg][tid] = run; run += t; }
        total[blockIdx.x * 16 + tid] = run;
    }
    __syncthreads();

    int run = p[g][j];
    for (int c = c0; c < c1; ++c) {
        int h = chunk_hist[(size_t)c * NBK + bkt];
        gdelta[(size_t)c * NBK + bkt] = run;
        run += h;
    }
}

// single block of 1024: exclusive scan of total -> base (+ sentinel)
__global__ void k_top(const int* __restrict__ total, int* __restrict__ base, int ne) {
    __shared__ int sm[NBK];
    int tid = threadIdx.x;
    int v = total[tid];
    sm[tid] = v;
    __syncthreads();
    for (int off = 1; off < NBK; off <<= 1) {
        int t = (tid >= off) ? sm[tid - off] : 0;
        __syncthreads();
        sm[tid] += t;
        __syncthreads();
    }
    base[tid] = sm[tid] - v;
    if (tid == 0) base[NBK] = ne;
}

// staged bin: positions fully precomputed (no global atomics, no re-histogram).
// LDS counting-sort the chunk by bucket (int2 stage), coalesced write-out, O(1) lookup.
__global__ void __launch_bounds__(256)
k_bin(const int* __restrict__ src, const int* __restrict__ dst,
      const unsigned short* __restrict__ chunk_hist, const int* __restrict__ gdelta,
      const int* __restrict__ base, int* __restrict__ binned, int ne) {
    __shared__ int gpos[NBK];
    __shared__ int lcur[NBK];
    __shared__ int ps[256];
    __shared__ int2 stage[EPB];
    int tid = threadIdx.x;
    int chunk = blockIdx.x;
    const unsigned short* ch = chunk_hist + (size_t)chunk * NBK;
    const int* gd = gdelta + (size_t)chunk * NBK;

    // load this chunk's hist row (4/thread) and block-scan -> local bases
    ushort4 hq = ((const ushort4*)ch)[tid];
    int h0 = hq.x, h1v = hq.y, h2 = hq.z, h3 = hq.w;
    int sum = h0 + h1v + h2 + h3;
    ps[tid] = sum;
    __syncthreads();
    for (int off = 1; off < 256; off <<= 1) {
        int v = (tid >= off) ? ps[tid - off] : 0;
        __syncthreads();
        ps[tid] += v;
        __syncthreads();
    }
    int excl = ps[tid] - sum;
    int lb0 = excl, lb1 = excl + h0, lb2 = lb1 + h1v, lb3 = lb2 + h2;
    int4 gdq = ((const int4*)gd)[tid];
    int4 bq  = ((const int4*)base)[tid];
    gpos[4 * tid + 0] = bq.x + gdq.x - lb0;
    gpos[4 * tid + 1] = bq.y + gdq.y - lb1;
    gpos[4 * tid + 2] = bq.z + gdq.z - lb2;
    gpos[4 * tid + 3] = bq.w + gdq.w - lb3;
    lcur[4 * tid + 0] = lb0;
    lcur[4 * tid + 1] = lb1;
    lcur[4 * tid + 2] = lb2;
    lcur[4 * tid + 3] = lb3;
    __syncthreads();

    int e0 = chunk * EPB;
    int csz = min(EPB, ne - e0);

    // local scatter into LDS stage (bucket-sorted within chunk), 8B per edge
    for (int i = tid; i < csz; i += 256) {
        int d = dst[e0 + i];
        int b = d >> 8;
        int r = atomicAdd(&lcur[b], 1);
        int2 sv;
        sv.x = src[e0 + i] | ((d & (NPB - 1)) << SRC_BITS);
        sv.y = b;
        stage[r] = sv;
    }
    __syncthreads();

    // coalesced write-out: consecutive lanes -> consecutive global positions per run
    for (int i = tid; i < csz; i += 256) {
        int2 sv = stage[i];
        binned[gpos[sv.y] + i] = sv.x;
    }
}

// block per dst-bucket: counting sort by dst-local index, STAGED in LDS for coalesced
// write-out -> node-contiguous binned2 (plain src), row_start[], dis[];
// FUSED h1: hs1 = fp16((x@W1)*dis).
__global__ void __launch_bounds__(512)
k_sort2(const int* __restrict__ base, const int* __restrict__ binned,
        int* __restrict__ binned2, int* __restrict__ row_start,
        float* __restrict__ dis, const float* __restrict__ x,
        const float* __restrict__ W1, __half* __restrict__ hs1,
        int n, int nb_total) {
    __shared__ int cnt[NPB];
    __shared__ int pos[NPB];
    __shared__ int cur[NPB];
    __shared__ float w[N_IN_F * N_HID];
    __shared__ int stage[STAGE_CAP];
    int tid = threadIdx.x;
    if (tid < NPB) cnt[tid] = 0;
    for (int t = tid; t < N_IN_F * N_HID; t += 512) w[t] = W1[t];
    __syncthreads();

    int b = blockIdx.x;
    int e0 = base[b], e1 = base[b + 1];
    int csz = e1 - e0;

    for (int e = e0 + tid; e < e1; e += 512) atomicAdd(&cnt[binned[e] >> SRC_BITS], 1);
    __syncthreads();

    int v = (tid < NPB) ? cnt[tid] : 0;
    if (tid < NPB) pos[tid] = v;
    __syncthreads();
    for (int off = 1; off < NPB; off <<= 1) {
        int t = (tid < NPB && tid >= off) ? pos[tid - off] : 0;
        __syncthreads();
        if (tid < NPB) pos[tid] += t;
        __syncthreads();
    }
    if (tid < NPB) {
        int excl = pos[tid] - v;           // exclusive prefix within bucket
        cur[tid] = excl;                   // stage-local cursor
        int g = b * NPB + tid;
        if (g < n) {
            row_start[g] = e0 + excl;
            dis[g] = rsqrtf((float)(v + 1));   // in-degree + self-loop
        }
    }
    if (b == nb_total - 1 && tid == 0) row_start[n] = e1;
    __syncthreads();

    // scatter into LDS stage (node-sorted within bucket); overflow -> direct store
    for (int e = e0 + tid; e < e1; e += 512) {
        int p = binned[e];
        int r = atomicAdd(&cur[p >> SRC_BITS], 1);
        int val = p & SRC_MASK;
        if (r < STAGE_CAP) stage[r] = val;
        else binned2[e0 + r] = val;
    }
    __syncthreads();

    // coalesced write-out
    int lim = min(csz, STAGE_CAP);
    for (int i = tid; i < lim; i += 512) binned2[e0 + i] = stage[i];

    // fused h1 for this bucket's 256 nodes (thread = node, tid < NPB)
    if (tid < NPB) {
        int g = b * NPB + tid;
        if (g < n) {
            float di = rsqrtf((float)(cnt[tid] + 1));
            float xi[N_IN_F];
            const float4* xr = (const float4*)(x + (size_t)g * N_IN_F);
#pragma unroll
            for (int q = 0; q < N_IN_F / 4; ++q) {
                float4 vv = xr[q];
                xi[4 * q + 0] = vv.x; xi[4 * q + 1] = vv.y;
                xi[4 * q + 2] = vv.z; xi[4 * q + 3] = vv.w;
            }
            __half2 hp[N_HID / 2];
#pragma unroll
            for (int f2 = 0; f2 < N_HID / 2; ++f2) {
                float ha = 0.0f, hb = 0.0f;
#pragma unroll
                for (int k = 0; k < N_IN_F; ++k) {
                    ha = fmaf(xi[k], w[k * N_HID + 2 * f2], ha);
                    hb = fmaf(xi[k], w[k * N_HID + 2 * f2 + 1], hb);
                }
                hp[f2] = __floats2half2_rn(ha * di, hb * di);
            }
            int4* dstp = (int4*)(hs1 + (size_t)g * N_HID);
            dstp[0] = *(const int4*)&hp[0];
            dstp[1] = *(const int4*)&hp[4];
        }
    }
}

// ---------------- compute ----------------

// 8 lanes per node (half2 per lane): register-accumulation gather, 8-edge unroll,
// fused relu + W2 + cross-lane reduce -> hs2 (fp32). NO LDS atomics.
__global__ void __launch_bounds__(256)
k_agg1(const int* __restrict__ row_start, const int* __restrict__ esrc,
       const __half2* __restrict__ hs1, const float* __restrict__ dis,
       const float* __restrict__ b1, const float* __restrict__ W2,
       float2* __restrict__ hs2, int n) {
    int t = blockIdx.x * blockDim.x + threadIdx.x;
    int node = t >> 3;
    int f2 = t & 7;
    if (node >= n) return;

    int beg = row_start[node];
    int end = row_start[node + 1];
    const __half2* H = hs1 + f2;           // H[s*8] = hs1[s*8 + f2]

    float2 sl = __half22float2(H[node * 8]);   // self-loop seed
    float ax = sl.x, ay = sl.y;
    float a0x = 0.f, a0y = 0.f, a1x = 0.f, a1y = 0.f;
    float a2x = 0.f, a2y = 0.f, a3x = 0.f, a3y = 0.f;
    int j = beg;
    for (; j + 8 <= end; j += 8) {
        int s0 = esrc[j],     s1 = esrc[j + 1], s2 = esrc[j + 2], s3 = esrc[j + 3];
        int s4 = esrc[j + 4], s5 = esrc[j + 5], s6 = esrc[j + 6], s7 = esrc[j + 7];
        float2 v0 = __half22float2(H[s0 * 8]);
        float2 v1 = __half22float2(H[s1 * 8]);
        float2 v2 = __half22float2(H[s2 * 8]);
        float2 v3 = __half22float2(H[s3 * 8]);
        float2 v4 = __half22float2(H[s4 * 8]);
        float2 v5 = __half22float2(H[s5 * 8]);
        float2 v6 = __half22float2(H[s6 * 8]);
        float2 v7 = __half22float2(H[s7 * 8]);
        a0x += v0.x; a0y += v0.y; a1x += v1.x; a1y += v1.y;
        a2x += v2.x; a2y += v2.y; a3x += v3.x; a3y += v3.y;
        a0x += v4.x; a0y += v4.y; a1x += v5.x; a1y += v5.y;
        a2x += v6.x; a2y += v6.y; a3x += v7.x; a3y += v7.y;
    }
    for (; j + 4 <= end; j += 4) {
        int s0 = esrc[j], s1 = esrc[j + 1], s2 = esrc[j + 2], s3 = esrc[j + 3];
        float2 v0 = __half22float2(H[s0 * 8]);
        float2 v1 = __half22float2(H[s1 * 8]);
        float2 v2 = __half22float2(H[s2 * 8]);
        float2 v3 = __half22float2(H[s3 * 8]);
        a0x += v0.x; a0y += v0.y; a1x += v1.x; a1y += v1.y;
        a2x += v2.x; a2y += v2.y; a3x += v3.x; a3y += v3.y;
    }
    for (; j < end; ++j) {
        float2 v0 = __half22float2(H[esrc[j] * 8]);
        ax += v0.x; ay += v0.y;
    }
    ax += (a0x + a1x) + (a2x + a3x);
    ay += (a0y + a1y) + (a2y + a3y);

    float di = dis[node];
    float vx = fmaxf(fmaf(di, ax, b1[2 * f2 + 0]), 0.0f);
    float vy = fmaxf(fmaf(di, ay, b1[2 * f2 + 1]), 0.0f);
    float c0 = vx * W2[4 * f2 + 0] + vy * W2[4 * f2 + 2];
    float c1 = vx * W2[4 * f2 + 1] + vy * W2[4 * f2 + 3];
#pragma unroll
    for (int off = 4; off > 0; off >>= 1) {
        c0 += __shfl_xor(c0, off, 8);
        c1 += __shfl_xor(c1, off, 8);
    }
    if (f2 == 0) {
        float2 o;
        o.x = c0 * di;
        o.y = c1 * di;
        hs2[node] = o;
    }
}

// 4 lanes per node, 2-deep unrolled gather of hs2 (float2, L2-resident) + fused log_softmax
__global__ void __launch_bounds__(256)
k_agg2(const int* __restrict__ row_start, const int* __restrict__ esrc,
       const float2* __restrict__ hs2, const float* __restrict__ dis,
       const float* __restrict__ b2, float2* __restrict__ out, int n) {
    int t = blockIdx.x * blockDim.x + threadIdx.x;
    int node = t >> 2;
    int l = t & 3;
    if (node >= n) return;

    int beg = row_start[node];
    int end = row_start[node + 1];
    float cx = 0.f, cy = 0.f, dx = 0.f, dy = 0.f;
    int j = beg + l;
    for (; j + 4 < end; j += 8) {
        int s0 = esrc[j];
        int s1 = esrc[j + 4];
        float2 v0 = hs2[s0];
        float2 v1 = hs2[s1];
        cx += v0.x; cy += v0.y;
        dx += v1.x; dy += v1.y;
    }
    if (j < end) {
        float2 v = hs2[esrc[j]];
        cx += v.x; cy += v.y;
    }
    cx += dx; cy += dy;
#pragma unroll
    for (int off = 2; off > 0; off >>= 1) {
        cx += __shfl_xor(cx, off, 4);
        cy += __shfl_xor(cy, off, 4);
    }
    if (l == 0) {
        float2 self = hs2[node];
        float di = dis[node];
        float a = fmaf(di, cx + self.x, b2[0]);
        float c = fmaf(di, cy + self.y, b2[1]);
        float m = fmaxf(a, c);
        float lse = m + logf(expf(a - m) + expf(c - m));
        float2 o;
        o.x = a - lse;
        o.y = c - lse;
        out[node] = o;
    }
}

// ---------------- launch ----------------

extern "C" void kernel_launch(void* const* d_in, const int* in_sizes, int n_in,
                              void* d_out, int out_size, void* d_ws, size_t ws_size,
                              hipStream_t stream) {
    const float* x  = (const float*)d_in[0];
    const int*   ei = (const int*)d_in[1];
    const float* W1 = (const float*)d_in[2];
    const float* b1 = (const float*)d_in[3];
    const float* W2 = (const float*)d_in[4];
    const float* b2 = (const float*)d_in[5];
    float2* out = (float2*)d_out;

    const int n  = in_sizes[0] / N_IN_F;   // 200000
    const int ne = in_sizes[1] / 2;        // 6400000
    const int* src = ei;
    const int* dst = ei + ne;
    const int nb = (n + NPB - 1) / NPB;    // 782 <= 1024
    const int nchunk = (ne + EPB - 1) / EPB;  // 1563

    // workspace layout (4B units), total ~64MB. Aliasing (ordering-safe):
    //   gdelta (nchunk*NBK ints) aliases binned2 (dead before k_sort2 writes binned2)
    //   chunk_hist, hs1 are STANDALONE
    int* ws_i = (int*)d_ws;
    int* total     = ws_i;                      // 1024
    int* base      = total + 1024;              // 1028 (NBK+1 used)
    int* row_start = base + 1028;               // n+4
    float* dis     = (float*)(row_start + n + 4);  // n
    float2* hs2    = (float2*)(dis + n);        // n float2 (2n floats)
    __half* hs1    = (__half*)(hs2 + n);        // 16n halfs = 8n ints
    unsigned short* chunk_hist = (unsigned short*)((int*)hs1 + 8 * (size_t)n);  // nchunk*NBK u16
    int* binned2   = (int*)chunk_hist + ((size_t)nchunk * NBK + 1) / 2;  // ne
    int* binned    = binned2 + ne;              // ne
    int* gdelta    = binned2;                   // alias (nchunk*NBK ints <= ne)

    const int B = 256;

    k_bhist<<<dim3(nchunk), dim3(B), 0, stream>>>(dst, chunk_hist, ne);
    k_colscan<<<dim3(NBK / 16), dim3(B), 0, stream>>>(chunk_hist, gdelta, total, nchunk);
    k_top<<<dim3(1), dim3(NBK), 0, stream>>>(total, base, ne);
    k_bin<<<dim3(nchunk), dim3(B), 0, stream>>>(src, dst, chunk_hist, gdelta, base, binned, ne);
    k_sort2<<<dim3(nb), dim3(512), 0, stream>>>(base, binned, binned2, row_start, dis,
                                                x, W1, hs1, n, nb);
    {
        long long tot = (long long)n * 8;
        k_agg1<<<dim3((unsigned)((tot + B - 1) / B)), dim3(B), 0, stream>>>(
            row_start, binned2, (const __half2*)hs1, dis, b1, W2, hs2, n);
    }
    {
        long long tot = (long long)n * 4;
        k_agg2<<<dim3((unsigned)((tot + B - 1) / B)), dim3(B), 0, stream>>>(
            row_start, binned2, hs2, dis, b2, out, n);
    }
}

// Round 12
// 220.840 us; speedup vs baseline: 5.1799x; 1.0254x over previous
//
#include <hip/hip_runtime.h>
#include <hip/hip_fp16.h>
#include <math.h>

#define N_IN_F 28
#define N_HID 16
#define NPB 256              // nodes per dst-bucket (bucket = dst >> 8)
#define NBK 1024             // bucket table size (782 actual)
#define EPB 8192             // edges per chunk (bhist/bin blocks)
#define SRC_BITS 18
#define SRC_MASK ((1 << SRC_BITS) - 1)
#define STAGE_CAP 10240      // LDS stage entries for k_sort2 (bucket mean 8192, sigma ~90)

// ---------------- build: chunk histograms -> column scans -> staged bin -> staged sort+h1 ----------------

// chunk histogram of dst>>8, saved to global (u16, coalesced). No global atomics.
__global__ void __launch_bounds__(256)
k_bhist(const int* __restrict__ dst, unsigned short* __restrict__ chunk_hist, int ne) {
    __shared__ int hist[NBK];
    int tid = threadIdx.x;
    for (int t = tid; t < NBK; t += 256) hist[t] = 0;
    __syncthreads();
    int e0 = blockIdx.x * EPB;
    int e1 = min(e0 + EPB, ne);
    for (int e = e0 + tid; e < e1; e += 256) atomicAdd(&hist[dst[e] >> 8], 1);
    __syncthreads();
    unsigned short* ch = chunk_hist + (size_t)blockIdx.x * NBK;
    for (int t = tid; t < NBK; t += 256) ch[t] = (unsigned short)hist[t];
}

// 64 blocks x 16 buckets: per-bucket exclusive scan across chunks -> gdelta[chunk][bucket],
// plus per-bucket totals.
__global__ void __launch_bounds__(256)
k_colscan(const unsigned short* __restrict__ chunk_hist, int* __restrict__ gdelta,
          int* __restrict__ total, int nchunk) {
    __shared__ int p[16][17];
    int tid = threadIdx.x;
    int j = tid & 15;              // bucket lane within block's 16 buckets
    int g = tid >> 4;              // chunk-group
    int bkt = blockIdx.x * 16 + j;
    int cpg = (nchunk + 15) >> 4;
    int c0 = g * cpg, c1 = min(c0 + cpg, nchunk);

    int s = 0;
    for (int c = c0; c < c1; ++c) s += chunk_hist[(size_t)c * NBK + bkt];
    p[g][j] = s;
    __syncthreads();

    if (tid < 16) {                // serial scan over 16 groups for bucket tid
        int run = 0;
#pragma unroll
        for (int gg = 0; gg < 16; ++gg) { int t = p[gg][tid]; p[gg][tid] = run; run += t; }
        total[blockIdx.x * 16 + tid] = run;
    }
    __syncthreads();

    int run = p[g][j];
    for (int c = c0; c < c1; ++c) {
        int h = chunk_hist[(size_t)c * NBK + bkt];
        gdelta[(size_t)c * NBK + bkt] = run;
        run += h;
    }
}

// single block of 1024: exclusive scan of total -> base (+ sentinel)
__global__ void k_top(const int* __restrict__ total, int* __restrict__ base, int ne) {
    __shared__ int sm[NBK];
    int tid = threadIdx.x;
    int v = total[tid];
    sm[tid] = v;
    __syncthreads();
    for (int off = 1; off < NBK; off <<= 1) {
        int t = (tid >= off) ? sm[tid - off] : 0;
        __syncthreads();
        sm[tid] += t;
        __syncthreads();
    }
    base[tid] = sm[tid] - v;
    if (tid == 0) base[NBK] = ne;
}

// staged bin: positions fully precomputed (no global atomics, no re-histogram).
// LDS counting-sort the chunk by bucket (int2 stage), coalesced write-out, O(1) lookup.
__global__ void __launch_bounds__(512)
k_bin(const int* __restrict__ src, const int* __restrict__ dst,
      const unsigned short* __restrict__ chunk_hist, const int* __restrict__ gdelta,
      const int* __restrict__ base, int* __restrict__ binned, int ne) {
    __shared__ int gpos[NBK];
    __shared__ int lcur[NBK];
    __shared__ int ps[512];
    __shared__ int2 stage[EPB];    // 64 KB
    int tid = threadIdx.x;
    int chunk = blockIdx.x;
    const unsigned short* ch = chunk_hist + (size_t)chunk * NBK;
    const int* gd = gdelta + (size_t)chunk * NBK;

    // load this chunk's hist row (2/thread) and block-scan -> local bases
    ushort2 hq = ((const ushort2*)ch)[tid];
    int h0 = hq.x, h1v = hq.y;
    int sum = h0 + h1v;
    ps[tid] = sum;
    __syncthreads();
    for (int off = 1; off < 512; off <<= 1) {
        int v = (tid >= off) ? ps[tid - off] : 0;
        __syncthreads();
        ps[tid] += v;
        __syncthreads();
    }
    int excl = ps[tid] - sum;
    int lb0 = excl, lb1 = excl + h0;
    int2 gdq = ((const int2*)gd)[tid];
    int2 bq  = ((const int2*)base)[tid];
    gpos[2 * tid + 0] = bq.x + gdq.x - lb0;
    gpos[2 * tid + 1] = bq.y + gdq.y - lb1;
    lcur[2 * tid + 0] = lb0;
    lcur[2 * tid + 1] = lb1;
    __syncthreads();

    int e0 = chunk * EPB;
    int csz = min(EPB, ne - e0);

    // local scatter into LDS stage (bucket-sorted within chunk), 8B per edge
    for (int i = tid; i < csz; i += 512) {
        int d = dst[e0 + i];
        int b = d >> 8;
        int r = atomicAdd(&lcur[b], 1);
        int2 sv;
        sv.x = src[e0 + i] | ((d & (NPB - 1)) << SRC_BITS);
        sv.y = b;
        stage[r] = sv;
    }
    __syncthreads();

    // coalesced write-out: consecutive lanes -> consecutive global positions per run
    for (int i = tid; i < csz; i += 512) {
        int2 sv = stage[i];
        binned[gpos[sv.y] + i] = sv.x;
    }
}

// block per dst-bucket: counting sort by dst-local index, STAGED in LDS for coalesced
// write-out -> node-contiguous binned2 (plain src), row_start[], dis[];
// FUSED h1: hs1_lo/hs1_hi = fp16((x@W1)*dis), split into two 8-feature tables.
__global__ void __launch_bounds__(512)
k_sort2(const int* __restrict__ base, const int* __restrict__ binned,
        int* __restrict__ binned2, int* __restrict__ row_start,
        float* __restrict__ dis, const float* __restrict__ x,
        const float* __restrict__ W1, __half* __restrict__ hs1_lo,
        __half* __restrict__ hs1_hi, int n, int nb_total) {
    __shared__ int cnt[NPB];
    __shared__ int pos[NPB];
    __shared__ int cur[NPB];
    __shared__ float w[N_IN_F * N_HID];
    __shared__ int stage[STAGE_CAP];
    int tid = threadIdx.x;
    if (tid < NPB) cnt[tid] = 0;
    for (int t = tid; t < N_IN_F * N_HID; t += 512) w[t] = W1[t];
    __syncthreads();

    int b = blockIdx.x;
    int e0 = base[b], e1 = base[b + 1];
    int csz = e1 - e0;

    for (int e = e0 + tid; e < e1; e += 512) atomicAdd(&cnt[binned[e] >> SRC_BITS], 1);
    __syncthreads();

    int v = (tid < NPB) ? cnt[tid] : 0;
    if (tid < NPB) pos[tid] = v;
    __syncthreads();
    for (int off = 1; off < NPB; off <<= 1) {
        int t = (tid < NPB && tid >= off) ? pos[tid - off] : 0;
        __syncthreads();
        if (tid < NPB) pos[tid] += t;
        __syncthreads();
    }
    if (tid < NPB) {
        int excl = pos[tid] - v;           // exclusive prefix within bucket
        cur[tid] = excl;                   // stage-local cursor
        int g = b * NPB + tid;
        if (g < n) {
            row_start[g] = e0 + excl;
            dis[g] = rsqrtf((float)(v + 1));   // in-degree + self-loop
        }
    }
    if (b == nb_total - 1 && tid == 0) row_start[n] = e1;
    __syncthreads();

    // scatter into LDS stage (node-sorted within bucket); overflow -> direct store
    for (int e = e0 + tid; e < e1; e += 512) {
        int p = binned[e];
        int r = atomicAdd(&cur[p >> SRC_BITS], 1);
        int val = p & SRC_MASK;
        if (r < STAGE_CAP) stage[r] = val;
        else binned2[e0 + r] = val;
    }
    __syncthreads();

    // coalesced write-out
    int lim = min(csz, STAGE_CAP);
    for (int i = tid; i < lim; i += 512) binned2[e0 + i] = stage[i];

    // fused h1 for this bucket's 256 nodes (thread = node, tid < NPB)
    if (tid < NPB) {
        int g = b * NPB + tid;
        if (g < n) {
            float di = rsqrtf((float)(cnt[tid] + 1));
            float xi[N_IN_F];
            const float4* xr = (const float4*)(x + (size_t)g * N_IN_F);
#pragma unroll
            for (int q = 0; q < N_IN_F / 4; ++q) {
                float4 vv = xr[q];
                xi[4 * q + 0] = vv.x; xi[4 * q + 1] = vv.y;
                xi[4 * q + 2] = vv.z; xi[4 * q + 3] = vv.w;
            }
            __half2 hp[N_HID / 2];
#pragma unroll
            for (int f2 = 0; f2 < N_HID / 2; ++f2) {
                float ha = 0.0f, hb = 0.0f;
#pragma unroll
                for (int k = 0; k < N_IN_F; ++k) {
                    ha = fmaf(xi[k], w[k * N_HID + 2 * f2], ha);
                    hb = fmaf(xi[k], w[k * N_HID + 2 * f2 + 1], hb);
                }
                hp[f2] = __floats2half2_rn(ha * di, hb * di);
            }
            ((int4*)hs1_lo)[g] = *(const int4*)&hp[0];   // features 0..7
            ((int4*)hs1_hi)[g] = *(const int4*)&hp[4];   // features 8..15
        }
    }
}

// ---------------- compute ----------------

// half-feature aggregation pass: 4 lanes per node (half2 per lane), 8-edge unroll.
// Table is 3.2MB -> per-XCD L2-resident. FH=0: write partial W2-dot to hs2p.
// FH=1: add partial, finish (relu'd dot already folded), write hs2 = di*(cA+cB).
template <int FH>
__global__ void __launch_bounds__(256)
k_agg1h(const int* __restrict__ row_start, const int* __restrict__ esrc,
        const __half2* __restrict__ tbl, const float* __restrict__ dis,
        const float* __restrict__ b1, const float* __restrict__ W2,
        float2* __restrict__ hs2p, float2* __restrict__ hs2, int n) {
    int t = blockIdx.x * blockDim.x + threadIdx.x;
    int node = t >> 2;
    int f2 = t & 3;
    if (node >= n) return;

    int beg = row_start[node];
    int end = row_start[node + 1];
    const __half2* H = tbl + f2;           // H[s*4] = features {2f2, 2f2+1} of node s

    float2 sl = __half22float2(H[node * 4]);   // self-loop seed
    float ax = sl.x, ay = sl.y;
    float a0x = 0.f, a0y = 0.f, a1x = 0.f, a1y = 0.f;
    float a2x = 0.f, a2y = 0.f, a3x = 0.f, a3y = 0.f;
    int j = beg;
    for (; j + 8 <= end; j += 8) {
        int s0 = esrc[j],     s1 = esrc[j + 1], s2 = esrc[j + 2], s3 = esrc[j + 3];
        int s4 = esrc[j + 4], s5 = esrc[j + 5], s6 = esrc[j + 6], s7 = esrc[j + 7];
        float2 v0 = __half22float2(H[s0 * 4]);
        float2 v1 = __half22float2(H[s1 * 4]);
        float2 v2 = __half22float2(H[s2 * 4]);
        float2 v3 = __half22float2(H[s3 * 4]);
        float2 v4 = __half22float2(H[s4 * 4]);
        float2 v5 = __half22float2(H[s5 * 4]);
        float2 v6 = __half22float2(H[s6 * 4]);
        float2 v7 = __half22float2(H[s7 * 4]);
        a0x += v0.x; a0y += v0.y; a1x += v1.x; a1y += v1.y;
        a2x += v2.x; a2y += v2.y; a3x += v3.x; a3y += v3.y;
        a0x += v4.x; a0y += v4.y; a1x += v5.x; a1y += v5.y;
        a2x += v6.x; a2y += v6.y; a3x += v7.x; a3y += v7.y;
    }
    for (; j + 4 <= end; j += 4) {
        int s0 = esrc[j], s1 = esrc[j + 1], s2 = esrc[j + 2], s3 = esrc[j + 3];
        float2 v0 = __half22float2(H[s0 * 4]);
        float2 v1 = __half22float2(H[s1 * 4]);
        float2 v2 = __half22float2(H[s2 * 4]);
        float2 v3 = __half22float2(H[s3 * 4]);
        a0x += v0.x; a0y += v0.y; a1x += v1.x; a1y += v1.y;
        a2x += v2.x; a2y += v2.y; a3x += v3.x; a3y += v3.y;
    }
    for (; j < end; ++j) {
        float2 v0 = __half22float2(H[esrc[j] * 4]);
        ax += v0.x; ay += v0.y;
    }
    ax += (a0x + a1x) + (a2x + a3x);
    ay += (a0y + a1y) + (a2y + a3y);

    float di = dis[node];
    int feat = FH * 8 + 2 * f2;
    float vx = fmaxf(fmaf(di, ax, b1[feat + 0]), 0.0f);
    float vy = fmaxf(fmaf(di, ay, b1[feat + 1]), 0.0f);
    float c0 = vx * W2[2 * feat + 0] + vy * W2[2 * feat + 2];
    float c1 = vx * W2[2 * feat + 1] + vy * W2[2 * feat + 3];
#pragma unroll
    for (int off = 2; off > 0; off >>= 1) {
        c0 += __shfl_xor(c0, off, 4);
        c1 += __shfl_xor(c1, off, 4);
    }
    if (f2 == 0) {
        if (FH == 0) {
            float2 o; o.x = c0; o.y = c1;
            hs2p[node] = o;
        } else {
            float2 p = hs2p[node];
            float2 o;
            o.x = (p.x + c0) * di;
            o.y = (p.y + c1) * di;
            hs2[node] = o;
        }
    }
}

// 4 lanes per node, 2-deep unrolled gather of hs2 (float2, L2-resident) + fused log_softmax
__global__ void __launch_bounds__(256)
k_agg2(const int* __restrict__ row_start, const int* __restrict__ esrc,
       const float2* __restrict__ hs2, const float* __restrict__ dis,
       const float* __restrict__ b2, float2* __restrict__ out, int n) {
    int t = blockIdx.x * blockDim.x + threadIdx.x;
    int node = t >> 2;
    int l = t & 3;
    if (node >= n) return;

    int beg = row_start[node];
    int end = row_start[node + 1];
    float cx = 0.f, cy = 0.f, dx = 0.f, dy = 0.f;
    int j = beg + l;
    for (; j + 4 < end; j += 8) {
        int s0 = esrc[j];
        int s1 = esrc[j + 4];
        float2 v0 = hs2[s0];
        float2 v1 = hs2[s1];
        cx += v0.x; cy += v0.y;
        dx += v1.x; dy += v1.y;
    }
    if (j < end) {
        float2 v = hs2[esrc[j]];
        cx += v.x; cy += v.y;
    }
    cx += dx; cy += dy;
#pragma unroll
    for (int off = 2; off > 0; off >>= 1) {
        cx += __shfl_xor(cx, off, 4);
        cy += __shfl_xor(cy, off, 4);
    }
    if (l == 0) {
        float2 self = hs2[node];
        float di = dis[node];
        float a = fmaf(di, cx + self.x, b2[0]);
        float c = fmaf(di, cy + self.y, b2[1]);
        float m = fmaxf(a, c);
        float lse = m + logf(expf(a - m) + expf(c - m));
        float2 o;
        o.x = a - lse;
        o.y = c - lse;
        out[node] = o;
    }
}

// ---------------- launch ----------------

extern "C" void kernel_launch(void* const* d_in, const int* in_sizes, int n_in,
                              void* d_out, int out_size, void* d_ws, size_t ws_size,
                              hipStream_t stream) {
    const float* x  = (const float*)d_in[0];
    const int*   ei = (const int*)d_in[1];
    const float* W1 = (const float*)d_in[2];
    const float* b1 = (const float*)d_in[3];
    const float* W2 = (const float*)d_in[4];
    const float* b2 = (const float*)d_in[5];
    float2* out = (float2*)d_out;

    const int n  = in_sizes[0] / N_IN_F;   // 200000
    const int ne = in_sizes[1] / 2;        // 6400000
    const int* src = ei;
    const int* dst = ei + ne;
    const int nb = (n + NPB - 1) / NPB;    // 782 <= 1024
    const int nchunk = (ne + EPB - 1) / EPB;  // 782

    // workspace layout (4B units), total ~64MB. Aliasing (ordering-safe):
    //   gdelta (nchunk*NBK ints) aliases binned2 (dead before k_sort2 writes binned2)
    //   chunk_hist, hs1_lo/hi, hs2p are STANDALONE
    int* ws_i = (int*)d_ws;
    int* total     = ws_i;                      // 1024
    int* base      = total + 1024;              // 1028 (NBK+1 used)
    int* row_start = base + 1028;               // n+4
    float* dis     = (float*)(row_start + n + 4);  // n
    float2* hs2    = (float2*)(dis + n);        // n float2 (2n floats)
    float2* hs2p   = hs2 + n;                   // n float2 (2n floats)
    __half* hs1_lo = (__half*)(hs2p + n);       // 8n halfs = 4n ints
    __half* hs1_hi = hs1_lo + 8 * (size_t)n;    // 8n halfs = 4n ints
    unsigned short* chunk_hist = (unsigned short*)(hs1_hi + 8 * (size_t)n);  // nchunk*NBK u16
    int* binned2   = (int*)chunk_hist + ((size_t)nchunk * NBK + 1) / 2;  // ne
    int* binned    = binned2 + ne;              // ne
    int* gdelta    = binned2;                   // alias (nchunk*NBK ints <= ne)

    const int B = 256;

    k_bhist<<<dim3(nchunk), dim3(B), 0, stream>>>(dst, chunk_hist, ne);
    k_colscan<<<dim3(NBK / 16), dim3(B), 0, stream>>>(chunk_hist, gdelta, total, nchunk);
    k_top<<<dim3(1), dim3(NBK), 0, stream>>>(total, base, ne);
    k_bin<<<dim3(nchunk), dim3(512), 0, stream>>>(src, dst, chunk_hist, gdelta, base, binned, ne);
    k_sort2<<<dim3(nb), dim3(512), 0, stream>>>(base, binned, binned2, row_start, dis,
                                                x, W1, hs1_lo, hs1_hi, n, nb);
    {
        long long tot = (long long)n * 4;
        unsigned nbk = (unsigned)((tot + B - 1) / B);
        k_agg1h<0><<<dim3(nbk), dim3(B), 0, stream>>>(
            row_start, binned2, (const __half2*)hs1_lo, dis, b1, W2, hs2p, hs2, n);
        k_agg1h<1><<<dim3(nbk), dim3(B), 0, stream>>>(
            row_start, binned2, (const __half2*)hs1_hi, dis, b1, W2, hs2p, hs2, n);
        k_agg2<<<dim3(nbk), dim3(B), 0, stream>>>(
            row_start, binned2, hs2, dis, b2, out, n);
    }
}